// Round 15
// baseline (255.993 us; speedup 1.0000x reference)
//
#include <hip/hip_runtime.h>
#include <type_traits>

// ---------- types ----------
typedef short s8v   __attribute__((ext_vector_type(8)));   // 8 x bf16 bits
typedef float f32x4 __attribute__((ext_vector_type(4)));
typedef float f32x16 __attribute__((ext_vector_type(16)));
typedef unsigned int u32x2 __attribute__((ext_vector_type(2)));
typedef unsigned int u32x4 __attribute__((ext_vector_type(4)));

__device__ __forceinline__ unsigned short f2bf(float f) {
    unsigned int u = __builtin_bit_cast(unsigned int, f);
    u += 0x7FFF + ((u >> 16) & 1);          // round-to-nearest-even
    return (unsigned short)(u >> 16);
}
__device__ __forceinline__ float bf2f(unsigned short b) {
    unsigned int u = ((unsigned int)b) << 16;
    return __builtin_bit_cast(float, u);
}
__device__ __forceinline__ unsigned int cvtpk(float lo, float hi) {
    unsigned int w;
    asm("v_cvt_pk_bf16_f32 %0, %1, %2" : "=v"(w) : "v"(lo), "v"(hi));
    return w;
}

__device__ __forceinline__ void gload16(const void* g, void* l) {
    __builtin_amdgcn_global_load_lds(
        (const __attribute__((address_space(1))) void*)g,
        (__attribute__((address_space(3))) void*)l, 16, 0, 0);
}

// ---------- merged preprocessing: x->bf16 conv + wq/wk/wv transpose + wo transpose ----------
__global__ __launch_bounds__(256)
void prep_kernel(const float* __restrict__ x, const float* __restrict__ wq,
                 const float* __restrict__ wk, const float* __restrict__ wv,
                 const float* __restrict__ wo,
                 unsigned short* __restrict__ xb, unsigned short* __restrict__ wqkvT,
                 unsigned short* __restrict__ woT) {
    __shared__ float tile[32][33];
    const int bid = blockIdx.x;
    if (bid < 4096) {
        int i = bid * 256 + threadIdx.x;
        const f32x4* s4 = (const f32x4*)x;
        f32x4 a = s4[2 * i], b = s4[2 * i + 1];
        s8v o;
        o[0] = (short)f2bf(a[0]); o[1] = (short)f2bf(a[1]);
        o[2] = (short)f2bf(a[2]); o[3] = (short)f2bf(a[3]);
        o[4] = (short)f2bf(b[0]); o[5] = (short)f2bf(b[1]);
        o[6] = (short)f2bf(b[2]); o[7] = (short)f2bf(b[3]);
        *(s8v*)(xb + (size_t)i * 8) = o;
        return;
    }
    const int tx = threadIdx.x & 31, ty = threadIdx.x >> 5;
    const float* src; unsigned short* dst; int sc, N, n0, k0;
    if (bid < 10240) {
        int lb = bid - 4096;
        n0 = (lb % 96) * 32; k0 = (lb / 96) * 32;
        if (n0 < 2048)      { src = wq; sc = n0;        N = 2048; }
        else if (n0 < 2560) { src = wk; sc = n0 - 2048; N = 512;  }
        else                { src = wv; sc = n0 - 2560; N = 512;  }
        dst = wqkvT;
    } else {
        int lb = bid - 10240;
        n0 = (lb % 64) * 32; k0 = (lb / 64) * 32;
        src = wo; sc = n0; N = 2048; dst = woT;
    }
#pragma unroll
    for (int r = 0; r < 4; ++r)
        tile[ty + r * 8][tx] = src[(size_t)(k0 + ty + r * 8) * N + sc + tx];
    __syncthreads();
#pragma unroll
    for (int r = 0; r < 4; ++r)
        dst[(size_t)(n0 + ty + r * 8) * 2048 + k0 + tx] = f2bf(tile[tx][ty + r * 8]);
}

// ---------- RoPE (+q scale*log2e fold) and V->V^T, one launch ----------
// blocks [0,5120): rope in-place on qkvb; q cols get rope * (1/sqrt(128) * log2(e))
//   so attention scores are directly in log2 domain (exp2 softmax, no per-score mul).
// blocks [5120,7168): vtrans of V cols -> vt [b][kvh][128][2048]
__global__ __launch_bounds__(256)
void ropevt_kernel(unsigned short* __restrict__ qkv, const float* __restrict__ fc,
                   const float* __restrict__ fs, unsigned short* __restrict__ vt) {
    __shared__ unsigned short t[32][33];
    const int bid = blockIdx.x;
    if (bid < 5120) {
        int idx = bid * 256 + threadIdx.x;
        int grp = idx & 15;
        int hh = (idx >> 4) % 20;
        int row = idx / (16 * 20);
        int s = row & 2047;
        int col0 = (hh < 16 ? hh * 128 : 2048 + (hh - 16) * 128) + grp * 8;
        unsigned short* p = qkv + (size_t)row * 3072 + col0;
        s8v v = *(const s8v*)p;
        const float* cc = fc + (size_t)s * 64 + grp * 4;
        const float* ss = fs + (size_t)s * 64 + grp * 4;
        const float sc = (hh < 16) ? (0.08838834764831845f * 1.4426950408889634f) : 1.0f;
#pragma unroll
        for (int j = 0; j < 4; ++j) {
            float xe = bf2f((unsigned short)v[2 * j]);
            float xo = bf2f((unsigned short)v[2 * j + 1]);
            float c = cc[j], sn = ss[j];
            v[2 * j]     = (short)f2bf((xe * c - xo * sn) * sc);
            v[2 * j + 1] = (short)f2bf((xe * sn + xo * c) * sc);
        }
        *(s8v*)p = v;
        return;
    }
    int vb = bid - 5120;               // 0..2047
    int s0 = (vb & 127) * 32, c0 = (vb >> 7) * 32;
    int tx = threadIdx.x & 31, ty = threadIdx.x >> 5;
#pragma unroll
    for (int r = 0; r < 4; ++r)
        t[ty + r * 8][tx] = qkv[(size_t)(s0 + ty + r * 8) * 3072 + 2560 + c0 + tx];
    __syncthreads();
    int b = s0 >> 11, s = s0 & 2047;
    size_t dbase = (size_t)(b * 4 + (c0 >> 7)) * 128 + (c0 & 127);
#pragma unroll
    for (int r = 0; r < 4; ++r)
        vt[(dbase + ty + r * 8) * 2048 + s + tx] = t[tx][ty + r * 8];
}

// ---------- GEMM (R14 kernel, unchanged — measured good): C = A(MxK) * B^T(NxK) ----------
template <typename CT>
__global__ __launch_bounds__(256)
void gemm_bt(const unsigned short* __restrict__ A, const unsigned short* __restrict__ BT,
             CT* __restrict__ C, int M, int N, int K, int ldc) {
    __shared__ unsigned short As[128 * 64];
    __shared__ unsigned short Bs[128 * 64];
    const int tid = threadIdx.x;
    const int wid = tid >> 6, lane = tid & 63;
    const int l31 = lane & 31, h2 = lane >> 5;
    const int nbx = N >> 7;
    const int per = nbx >> 3;
    const int xcd = blockIdx.x & 7;
    const int li  = blockIdx.x >> 3;
    const int bx  = xcd * per + (li % per);
    const int by  = li / per;
    const int brow = by * 128, bcol = bx * 128;
    const int wr = wid >> 1, wc = wid & 1;
    f32x16 acc[2][2] = {};

    for (int kt = 0; kt < K; kt += 64) {
#pragma unroll
        for (int i = 0; i < 4; ++i) {
            int c = i * 256 + tid;
            int row = c >> 3, u = c & 7;
            gload16(A + (size_t)(brow + row) * K + kt + ((u ^ (row & 7)) << 3),
                    As + (size_t)c * 8);
            gload16(BT + (size_t)(bcol + row) * K + kt + ((u ^ (row & 7)) << 3),
                    Bs + (size_t)c * 8);
        }
        __syncthreads();
        s8v a[2][4], b[2][4];
#pragma unroll
        for (int mm = 0; mm < 2; ++mm) {
            int row = wr * 64 + mm * 32 + l31;
#pragma unroll
            for (int ks = 0; ks < 4; ++ks)
                a[mm][ks] = *(const s8v*)(As + (size_t)row * 64 +
                                          (((2 * ks + h2) ^ (row & 7)) << 3));
        }
#pragma unroll
        for (int nn = 0; nn < 2; ++nn) {
            int row = wc * 64 + nn * 32 + l31;
#pragma unroll
            for (int ks = 0; ks < 4; ++ks)
                b[nn][ks] = *(const s8v*)(Bs + (size_t)row * 64 +
                                          (((2 * ks + h2) ^ (row & 7)) << 3));
        }
#pragma unroll
        for (int ks = 0; ks < 4; ++ks)
#pragma unroll
            for (int mm = 0; mm < 2; ++mm)
#pragma unroll
                for (int nn = 0; nn < 2; ++nn)
                    acc[mm][nn] = __builtin_amdgcn_mfma_f32_32x32x16_bf16(
                        a[mm][ks], b[nn][ks], acc[mm][nn], 0, 0, 0);
        __syncthreads();
    }
#pragma unroll
    for (int mm = 0; mm < 2; ++mm)
#pragma unroll
        for (int nn = 0; nn < 2; ++nn)
#pragma unroll
            for (int reg = 0; reg < 16; ++reg) {
                int r = brow + wr * 64 + mm * 32 + (reg & 3) + 8 * (reg >> 2) + 4 * h2;
                int c = bcol + wc * 64 + nn * 32 + l31;
                float v = acc[mm][nn][reg];
                if constexpr (std::is_same<CT, float>::value)
                    C[(size_t)r * ldc + c] = v;
                else
                    C[(size_t)r * ldc + c] = f2bf(v);
            }
}

// ---------- Flash attention with flash-decoding split (balanced units) ----------
// 768 blocks x 256 threads (4 waves = 4 heads of one kvh). Unit decode:
//   u < 512 : SPLIT half-units of qi in [32,63]: pair=u>>1 -> qi=63-(pair>>3), g8=pair&7;
//             half0 = tiles [0,nt/2), half1 = [nt/2,nt). Writes (m,l,O_partial f32).
//   u >= 512: single units qi in [0,31]: full range, writes bf16 out directly.
// Max unit = 16 KV tiles (was 32) -> placement-independent tail reduction (R7/R9
// lesson: never assume dispatch topology; shrink the max unit instead).
// Body = R14-verified: swapped 32x32 QK^T (q lane-local), exp2-domain softmax
// (scores pre-scaled by log2e in rope), defer-max THR=11.5 (=8*log2e), mask only
// on the global diagonal tile (lives in half1/single), cvt_pk+shfl P-frag.
// Partial O goes to d_out (32MB, unused until gemm2 overwrites it); m/l to ws.
__global__ __launch_bounds__(256)
void attn_kernel(const unsigned short* __restrict__ qkv,
                 const unsigned short* __restrict__ vtg,
                 unsigned short* __restrict__ out,
                 float* __restrict__ opart, float* __restrict__ ml) {
    constexpr int S = 2048;
    __shared__ unsigned short Ks[2][64 * 128];   // [key][d-unit8 ^ (key&7)]
    __shared__ unsigned short Vs[2][128 * 64];   // [d][key-unit8 ^ (d&7)]
    const int tid = threadIdx.x, lane = tid & 63, wid = tid >> 6;
    const int l31 = lane & 31, h2 = lane >> 5;
    const int lsw = l31 & 7;

    const int u = blockIdx.x;
    int qi, g8, t0, t1, half = 0, split = 0;
    if (u < 512) {
        int pair = u >> 1; half = u & 1; split = 1;
        qi = 63 - (pair >> 3); g8 = pair & 7;
        int ntf0 = (qi >> 1) + 1, nth = ntf0 >> 1;
        t0 = half ? nth : 0; t1 = half ? ntf0 : nth;
    } else {
        int v2 = u - 512;
        qi = 31 - (v2 >> 3); g8 = v2 & 7;
        t0 = 0; t1 = (qi >> 1) + 1;
    }
    const int ntf = (qi >> 1) + 1;               // global tile count (diagonal = ntf-1)
    const int b = g8 >> 2, kvh = g8 & 3;
    const int h = kvh * 4 + wid;                 // wave = head
    const int qw = qi * 32;
    const int qq = qw + l31;
    const size_t rs = 3072;

    const unsigned short* Qp = qkv + (size_t)(b * S + qw) * rs + h * 128 + h2 * 8;
    const unsigned short* Kbase = qkv + (size_t)(b * S) * rs + 2048 + kvh * 128;
    const unsigned short* Vtg = vtg + (size_t)((b * 4 + kvh) * 128) * S;

    s8v qf[8];
#pragma unroll
    for (int kk = 0; kk < 8; ++kk)
        qf[kk] = *(const s8v*)(Qp + (size_t)l31 * rs + kk * 16);

    f32x16 acc[4] = {};                          // out^T: acc[dblk], row d, col q
    float m_run = -1e30f, l_run = 0.f;

    auto stage = [&](int t, int bufi) {
        const int kb64 = t * 64;
#pragma unroll
        for (int i = 0; i < 4; ++i) {
            int c = i * 256 + tid;
            int key = c >> 4, d8 = c & 15;
            gload16(Kbase + (size_t)(kb64 + key) * rs + ((d8 ^ (key & 7)) << 3),
                    &Ks[bufi][(size_t)c * 8]);
        }
#pragma unroll
        for (int i = 0; i < 4; ++i) {
            int c = i * 256 + tid;
            int d = c >> 3, k8 = c & 7;
            gload16(Vtg + (size_t)d * S + kb64 + ((k8 ^ (d & 7)) << 3),
                    &Vs[bufi][(size_t)c * 8]);
        }
    };

    int cur = 0;
    stage(t0, 0);
    __syncthreads();

    for (int t = t0; t < t1; ++t) {
        if (t + 1 < t1) stage(t + 1, cur ^ 1);
        const int kb64 = t * 64;
        const char* Kb = (const char*)&Ks[cur][0];
        const char* Vb = (const char*)&Vs[cur][0];

        s8v kf0[8], kf1[8];
#pragma unroll
        for (int kk = 0; kk < 8; ++kk)
            kf0[kk] = *(const s8v*)(Kb + l31 * 256 + (((2 * kk + h2) ^ lsw) << 4));
#pragma unroll
        for (int kk = 0; kk < 8; ++kk)
            kf1[kk] = *(const s8v*)(Kb + (32 + l31) * 256 + (((2 * kk + h2) ^ lsw) << 4));
        s8v vf[4][4];
#pragma unroll
        for (int kb = 0; kb < 4; ++kb)
#pragma unroll
            for (int dblk = 0; dblk < 4; ++dblk)
                vf[kb][dblk] = *(const s8v*)(Vb + (32 * dblk + l31) * 128 +
                                             (((2 * kb + h2) ^ lsw) << 4));

        f32x16 sacc0 = {}, sacc1 = {};
        __builtin_amdgcn_s_setprio(1);
#pragma unroll
        for (int kk = 0; kk < 8; ++kk)
            sacc0 = __builtin_amdgcn_mfma_f32_32x32x16_bf16(kf0[kk], qf[kk], sacc0, 0, 0, 0);
#pragma unroll
        for (int kk = 0; kk < 8; ++kk)
            sacc1 = __builtin_amdgcn_mfma_f32_32x32x16_bf16(kf1[kk], qf[kk], sacc1, 0, 0, 0);
        __builtin_amdgcn_s_setprio(0);

        // ---- scores (already log2-domain); mask only on the global diagonal tile ----
        float sv[32];
        if (t == ntf - 1) {
#pragma unroll
            for (int g = 0; g < 2; ++g)
#pragma unroll
                for (int r = 0; r < 16; ++r) {
                    int key = kb64 + 32 * g + (r & 3) + 8 * (r >> 2) + 4 * h2;
                    float s = (g ? sacc1[r] : sacc0[r]);
                    sv[g * 16 + r] = (key <= qq) ? s : -1e30f;
                }
        } else {
#pragma unroll
            for (int r = 0; r < 16; ++r) sv[r] = sacc0[r];
#pragma unroll
            for (int r = 0; r < 16; ++r) sv[16 + r] = sacc1[r];
        }

        // ---- online softmax (exp2 domain), q lane-local; defer-max THR=11.5 ----
        float mx = sv[0];
#pragma unroll
        for (int i = 1; i < 32; ++i) mx = fmaxf(mx, sv[i]);
        mx = fmaxf(mx, __shfl_xor(mx, 32));
        if (!__all(mx - m_run <= 11.5f)) {
            float mn = fmaxf(m_run, mx);
            float alpha = exp2f(m_run - mn);
            m_run = mn;
            l_run *= alpha;
#pragma unroll
            for (int dblk = 0; dblk < 4; ++dblk)
#pragma unroll
                for (int r = 0; r < 16; ++r) acc[dblk][r] *= alpha;
        }
        float ps = 0.f;
#pragma unroll
        for (int i = 0; i < 32; ++i) {
            float e = exp2f(sv[i] - m_run);
            sv[i] = e;
            ps += e;
        }
        ps += __shfl_xor(ps, 32);
        l_run += ps;

        // ---- P -> B-frag: cvt_pk pairs + lane^32 exchange ----
        unsigned int pw[4][4];
#pragma unroll
        for (int g = 0; g < 2; ++g) {
            unsigned int w[8];
#pragma unroll
            for (int j = 0; j < 8; ++j)
                w[j] = cvtpk(sv[g * 16 + 2 * j], sv[g * 16 + 2 * j + 1]);
#pragma unroll
            for (int uu = 0; uu < 2; ++uu) {
                unsigned int t0w = (unsigned)__shfl_xor((int)w[4 * uu + 0], 32);
                unsigned int t1w = (unsigned)__shfl_xor((int)w[4 * uu + 1], 32);
                unsigned int t2w = (unsigned)__shfl_xor((int)w[4 * uu + 2], 32);
                unsigned int t3w = (unsigned)__shfl_xor((int)w[4 * uu + 3], 32);
                pw[2 * g + uu][0] = h2 ? t2w : w[4 * uu + 0];
                pw[2 * g + uu][1] = h2 ? t3w : w[4 * uu + 1];
                pw[2 * g + uu][2] = h2 ? w[4 * uu + 2] : t0w;
                pw[2 * g + uu][3] = h2 ? w[4 * uu + 3] : t1w;
            }
        }

        // ---- PV ----
        __builtin_amdgcn_s_setprio(1);
#pragma unroll
        for (int kb = 0; kb < 4; ++kb) {
            u32x4 wv;
            wv[0] = pw[kb][0]; wv[1] = pw[kb][1]; wv[2] = pw[kb][2]; wv[3] = pw[kb][3];
            s8v pf = __builtin_bit_cast(s8v, wv);
#pragma unroll
            for (int dblk = 0; dblk < 4; ++dblk)
                acc[dblk] = __builtin_amdgcn_mfma_f32_32x32x16_bf16(vf[kb][dblk], pf, acc[dblk], 0, 0, 0);
        }
        __builtin_amdgcn_s_setprio(0);

        __syncthreads();
        cur ^= 1;
    }

    if (split) {
        // partial: O raw sums (f32) + (m,l); p = ((g8*4+wid)*32 + qi-32)*2 + half
        const int p = ((g8 * 4 + wid) * 32 + (qi - 32)) * 2 + half;
        float* Op = opart + ((size_t)p * 32 + l31) * 128 + 4 * h2;
#pragma unroll
        for (int dblk = 0; dblk < 4; ++dblk)
#pragma unroll
            for (int s = 0; s < 4; ++s) {
                f32x4 v;
                v[0] = acc[dblk][4 * s + 0]; v[1] = acc[dblk][4 * s + 1];
                v[2] = acc[dblk][4 * s + 2]; v[3] = acc[dblk][4 * s + 3];
                *(f32x4*)(Op + 32 * dblk + 8 * s) = v;
            }
        if (h2 == 0) {
            float2* ml2 = (float2*)ml;
            ml2[p * 32 + l31] = make_float2(m_run, l_run);
        }
    } else {
        float inv = 1.f / l_run;
        unsigned short* Opb = out + (size_t)(b * S + qq) * 2048 + h * 128 + 4 * h2;
#pragma unroll
        for (int dblk = 0; dblk < 4; ++dblk)
#pragma unroll
            for (int s = 0; s < 4; ++s) {
                u32x2 wv;
                wv[0] = cvtpk(acc[dblk][4 * s + 0] * inv, acc[dblk][4 * s + 1] * inv);
                wv[1] = cvtpk(acc[dblk][4 * s + 2] * inv, acc[dblk][4 * s + 3] * inv);
                *(u32x2*)(Opb + 32 * dblk + 8 * s) = wv;
            }
    }
}

// ---------- merge of split halves (flash-decoding combine) ----------
// 1024 blocks = (g8h = g8*4+hsub in [0,32), qi-32 in [0,32)); 256 threads:
// thread -> q = tid>>3 (32 rows), d0 = (tid&7)*16 (16 d-values).
__global__ __launch_bounds__(256)
void attn_merge(const float* __restrict__ opart, const float* __restrict__ ml,
                unsigned short* __restrict__ out) {
    const int mb = blockIdx.x;
    const int g8h = mb & 31;
    const int qi = 32 + (mb >> 5);
    const int g8 = g8h >> 2, hsub = g8h & 3;
    const int b = g8 >> 2, kvh = g8 & 3;
    const int h = kvh * 4 + hsub;
    const int p0 = (g8h * 32 + (qi - 32)) * 2, p1 = p0 + 1;
    const int tid = threadIdx.x;
    const int q = tid >> 3, d0 = (tid & 7) * 16;

    const float2* ml2 = (const float2*)ml;
    float2 a = ml2[p0 * 32 + q], c = ml2[p1 * 32 + q];
    float m = fmaxf(a.x, c.x);
    float w1 = exp2f(a.x - m), w2 = exp2f(c.x - m);
    float inv = 1.f / (w1 * a.y + w2 * c.y);
    w1 *= inv; w2 *= inv;
    const float* O0 = opart + ((size_t)p0 * 32 + q) * 128 + d0;
    const float* O1 = opart + ((size_t)p1 * 32 + q) * 128 + d0;
    unsigned int r[8];
#pragma unroll
    for (int i = 0; i < 4; ++i) {
        f32x4 v0 = *(const f32x4*)(O0 + 4 * i);
        f32x4 v1 = *(const f32x4*)(O1 + 4 * i);
        float x0 = w1 * v0[0] + w2 * v1[0];
        float x1 = w1 * v0[1] + w2 * v1[1];
        float x2 = w1 * v0[2] + w2 * v1[2];
        float x3 = w1 * v0[3] + w2 * v1[3];
        r[2 * i]     = cvtpk(x0, x1);
        r[2 * i + 1] = cvtpk(x2, x3);
    }
    unsigned short* Ob = out + (size_t)(b * 2048 + qi * 32 + q) * 2048 + h * 128 + d0;
    u32x4 w0; w0[0] = r[0]; w0[1] = r[1]; w0[2] = r[2]; w0[3] = r[3];
    u32x4 w1v; w1v[0] = r[4]; w1v[1] = r[5]; w1v[2] = r[6]; w1v[3] = r[7];
    *(u32x4*)Ob = w0;
    *(u32x4*)(Ob + 8) = w1v;
}

// ---------- launch ----------
extern "C" void kernel_launch(void* const* d_in, const int* in_sizes, int n_in,
                              void* d_out, int out_size, void* d_ws, size_t ws_size,
                              hipStream_t stream) {
    const float* x  = (const float*)d_in[0];
    const float* fc = (const float*)d_in[1];
    const float* fs = (const float*)d_in[2];
    const float* wq = (const float*)d_in[4];
    const float* wk = (const float*)d_in[5];
    const float* wv = (const float*)d_in[6];
    const float* wo = (const float*)d_in[7];
    float* out = (float*)d_out;

    char* ws = (char*)d_ws;
    unsigned short* xb    = (unsigned short*)ws;                               // 16 MB (reused as attn out)
    unsigned short* wqkvT = (unsigned short*)(ws + 16777216);                  // 12 MB (reused: V^T 4MB + ml 0.5MB)
    unsigned short* woT   = (unsigned short*)(ws + 16777216 + 12582912);       // 8 MB
    unsigned short* qkvb  = (unsigned short*)(ws + 16777216 + 12582912 + 8388608); // 24 MB
    unsigned short* attnb = xb;
    unsigned short* vtb   = wqkvT;                      // V^T [2][4][128][2048] = 4 MB
    float* mlbuf = (float*)(ws + 16777216 + 4194304);   // 512 KB (dead wqkvT tail)
    float* opart = out;                                 // 32 MB partials, overwritten by gemm2

    prep_kernel<<<14336, 256, 0, stream>>>(x, wq, wk, wv, wo, xb, wqkvT, woT);
    gemm_bt<unsigned short><<<768, 256, 0, stream>>>(
        xb, wqkvT, qkvb, 4096, 3072, 2048, 3072);
    ropevt_kernel<<<7168, 256, 0, stream>>>(qkvb, fc, fs, vtb);
    attn_kernel<<<768, 256, 0, stream>>>(qkvb, vtb, attnb, opart, mlbuf);
    attn_merge<<<1024, 256, 0, stream>>>(opart, mlbuf, attnb);
    gemm_bt<float><<<512, 256, 0, stream>>>(
        attnb, woT, out, 4096, 2048, 2048, 2048);
}

// Round 16
// 227.001 us; speedup vs baseline: 1.1277x; 1.1277x over previous
//
#include <hip/hip_runtime.h>
#include <type_traits>

// ---------- types ----------
typedef short s8v   __attribute__((ext_vector_type(8)));   // 8 x bf16 bits
typedef float f32x4 __attribute__((ext_vector_type(4)));
typedef float f32x16 __attribute__((ext_vector_type(16)));
typedef unsigned int u32x2 __attribute__((ext_vector_type(2)));
typedef unsigned int u32x4 __attribute__((ext_vector_type(4)));

__device__ __forceinline__ unsigned short f2bf(float f) {
    unsigned int u = __builtin_bit_cast(unsigned int, f);
    u += 0x7FFF + ((u >> 16) & 1);          // round-to-nearest-even
    return (unsigned short)(u >> 16);
}
__device__ __forceinline__ float bf2f(unsigned short b) {
    unsigned int u = ((unsigned int)b) << 16;
    return __builtin_bit_cast(float, u);
}
__device__ __forceinline__ unsigned int cvtpk(float lo, float hi) {
    unsigned int w;
    asm("v_cvt_pk_bf16_f32 %0, %1, %2" : "=v"(w) : "v"(lo), "v"(hi));
    return w;
}

__device__ __forceinline__ void gload16(const void* g, void* l) {
    __builtin_amdgcn_global_load_lds(
        (const __attribute__((address_space(1))) void*)g,
        (__attribute__((address_space(3))) void*)l, 16, 0, 0);
}

// ---------- merged preprocessing: x->bf16 conv + wq/wk/wv transpose + wo transpose ----------
__global__ __launch_bounds__(256)
void prep_kernel(const float* __restrict__ x, const float* __restrict__ wq,
                 const float* __restrict__ wk, const float* __restrict__ wv,
                 const float* __restrict__ wo,
                 unsigned short* __restrict__ xb, unsigned short* __restrict__ wqkvT,
                 unsigned short* __restrict__ woT) {
    __shared__ float tile[32][33];
    const int bid = blockIdx.x;
    if (bid < 4096) {
        int i = bid * 256 + threadIdx.x;
        const f32x4* s4 = (const f32x4*)x;
        f32x4 a = s4[2 * i], b = s4[2 * i + 1];
        s8v o;
        o[0] = (short)f2bf(a[0]); o[1] = (short)f2bf(a[1]);
        o[2] = (short)f2bf(a[2]); o[3] = (short)f2bf(a[3]);
        o[4] = (short)f2bf(b[0]); o[5] = (short)f2bf(b[1]);
        o[6] = (short)f2bf(b[2]); o[7] = (short)f2bf(b[3]);
        *(s8v*)(xb + (size_t)i * 8) = o;
        return;
    }
    const int tx = threadIdx.x & 31, ty = threadIdx.x >> 5;
    const float* src; unsigned short* dst; int sc, N, n0, k0;
    if (bid < 10240) {
        int lb = bid - 4096;
        n0 = (lb % 96) * 32; k0 = (lb / 96) * 32;
        if (n0 < 2048)      { src = wq; sc = n0;        N = 2048; }
        else if (n0 < 2560) { src = wk; sc = n0 - 2048; N = 512;  }
        else                { src = wv; sc = n0 - 2560; N = 512;  }
        dst = wqkvT;
    } else {
        int lb = bid - 10240;
        n0 = (lb % 64) * 32; k0 = (lb / 64) * 32;
        src = wo; sc = n0; N = 2048; dst = woT;
    }
#pragma unroll
    for (int r = 0; r < 4; ++r)
        tile[ty + r * 8][tx] = src[(size_t)(k0 + ty + r * 8) * N + sc + tx];
    __syncthreads();
#pragma unroll
    for (int r = 0; r < 4; ++r)
        dst[(size_t)(n0 + ty + r * 8) * 2048 + k0 + tx] = f2bf(tile[tx][ty + r * 8]);
}

// ---------- RoPE (+q scale*log2e fold) and V->V^T, one launch (R15-proven) ----------
// blocks [0,5120): rope in-place on qkvb; q cols get rope * (1/sqrt(128) * log2(e))
//   so attention scores are directly in log2 domain (exp2 softmax, no per-score mul).
// blocks [5120,7168): vtrans of V cols -> vt [b][kvh][128][2048]
__global__ __launch_bounds__(256)
void ropevt_kernel(unsigned short* __restrict__ qkv, const float* __restrict__ fc,
                   const float* __restrict__ fs, unsigned short* __restrict__ vt) {
    __shared__ unsigned short t[32][33];
    const int bid = blockIdx.x;
    if (bid < 5120) {
        int idx = bid * 256 + threadIdx.x;
        int grp = idx & 15;
        int hh = (idx >> 4) % 20;
        int row = idx / (16 * 20);
        int s = row & 2047;
        int col0 = (hh < 16 ? hh * 128 : 2048 + (hh - 16) * 128) + grp * 8;
        unsigned short* p = qkv + (size_t)row * 3072 + col0;
        s8v v = *(const s8v*)p;
        const float* cc = fc + (size_t)s * 64 + grp * 4;
        const float* ss = fs + (size_t)s * 64 + grp * 4;
        const float sc = (hh < 16) ? (0.08838834764831845f * 1.4426950408889634f) : 1.0f;
#pragma unroll
        for (int j = 0; j < 4; ++j) {
            float xe = bf2f((unsigned short)v[2 * j]);
            float xo = bf2f((unsigned short)v[2 * j + 1]);
            float c = cc[j], sn = ss[j];
            v[2 * j]     = (short)f2bf((xe * c - xo * sn) * sc);
            v[2 * j + 1] = (short)f2bf((xe * sn + xo * c) * sc);
        }
        *(s8v*)p = v;
        return;
    }
    int vb = bid - 5120;               // 0..2047
    int s0 = (vb & 127) * 32, c0 = (vb >> 7) * 32;
    int tx = threadIdx.x & 31, ty = threadIdx.x >> 5;
#pragma unroll
    for (int r = 0; r < 4; ++r)
        t[ty + r * 8][tx] = qkv[(size_t)(s0 + ty + r * 8) * 3072 + 2560 + c0 + tx];
    __syncthreads();
    int b = s0 >> 11, s = s0 & 2047;
    size_t dbase = (size_t)(b * 4 + (c0 >> 7)) * 128 + (c0 & 127);
#pragma unroll
    for (int r = 0; r < 4; ++r)
        vt[(dbase + ty + r * 8) * 2048 + s + tx] = t[tx][ty + r * 8];
}

// ---------- GEMM (R14 kernel, unchanged — measured good): C = A(MxK) * B^T(NxK) ----------
template <typename CT>
__global__ __launch_bounds__(256)
void gemm_bt(const unsigned short* __restrict__ A, const unsigned short* __restrict__ BT,
             CT* __restrict__ C, int M, int N, int K, int ldc) {
    __shared__ unsigned short As[128 * 64];
    __shared__ unsigned short Bs[128 * 64];
    const int tid = threadIdx.x;
    const int wid = tid >> 6, lane = tid & 63;
    const int l31 = lane & 31, h2 = lane >> 5;
    const int nbx = N >> 7;
    const int per = nbx >> 3;
    const int xcd = blockIdx.x & 7;
    const int li  = blockIdx.x >> 3;
    const int bx  = xcd * per + (li % per);
    const int by  = li / per;
    const int brow = by * 128, bcol = bx * 128;
    const int wr = wid >> 1, wc = wid & 1;
    f32x16 acc[2][2] = {};

    for (int kt = 0; kt < K; kt += 64) {
#pragma unroll
        for (int i = 0; i < 4; ++i) {
            int c = i * 256 + tid;
            int row = c >> 3, u = c & 7;
            gload16(A + (size_t)(brow + row) * K + kt + ((u ^ (row & 7)) << 3),
                    As + (size_t)c * 8);
            gload16(BT + (size_t)(bcol + row) * K + kt + ((u ^ (row & 7)) << 3),
                    Bs + (size_t)c * 8);
        }
        __syncthreads();
        s8v a[2][4], b[2][4];
#pragma unroll
        for (int mm = 0; mm < 2; ++mm) {
            int row = wr * 64 + mm * 32 + l31;
#pragma unroll
            for (int ks = 0; ks < 4; ++ks)
                a[mm][ks] = *(const s8v*)(As + (size_t)row * 64 +
                                          (((2 * ks + h2) ^ (row & 7)) << 3));
        }
#pragma unroll
        for (int nn = 0; nn < 2; ++nn) {
            int row = wc * 64 + nn * 32 + l31;
#pragma unroll
            for (int ks = 0; ks < 4; ++ks)
                b[nn][ks] = *(const s8v*)(Bs + (size_t)row * 64 +
                                          (((2 * ks + h2) ^ (row & 7)) << 3));
        }
#pragma unroll
        for (int ks = 0; ks < 4; ++ks)
#pragma unroll
            for (int mm = 0; mm < 2; ++mm)
#pragma unroll
                for (int nn = 0; nn < 2; ++nn)
                    acc[mm][nn] = __builtin_amdgcn_mfma_f32_32x32x16_bf16(
                        a[mm][ks], b[nn][ks], acc[mm][nn], 0, 0, 0);
        __syncthreads();
    }
#pragma unroll
    for (int mm = 0; mm < 2; ++mm)
#pragma unroll
        for (int nn = 0; nn < 2; ++nn)
#pragma unroll
            for (int reg = 0; reg < 16; ++reg) {
                int r = brow + wr * 64 + mm * 32 + (reg & 3) + 8 * (reg >> 2) + 4 * h2;
                int c = bcol + wc * 64 + nn * 32 + l31;
                float v = acc[mm][nn][reg];
                if constexpr (std::is_same<CT, float>::value)
                    C[(size_t)r * ldc + c] = v;
                else
                    C[(size_t)r * ldc + c] = f2bf(v);
            }
}

// ---------- Flash attention (R14 structure — measured best 95us) + exp2 softmax ----------
// 512 blocks x 256 threads (4 waves = 4 heads of one kvh). blockIdx&7 = (b,kvh).
// qi = 63 - (bid>>3): measured-best. Balance experiments PARKED (R7/R9/R15 all
// regressed: the schedule is not tail-bound; per-tile issue cost is the limiter).
// Scores arrive pre-scaled by 1/sqrt(128)*log2e (rope fold) -> exp2 softmax,
// defer-max THR=11.5 (=8*log2e). Mask only on the diagonal tile.
__global__ __launch_bounds__(256)
void attn_kernel(const unsigned short* __restrict__ qkv,
                 const unsigned short* __restrict__ vtg,
                 unsigned short* __restrict__ out) {
    constexpr int S = 2048;
    __shared__ unsigned short Ks[2][64 * 128];   // [key][d-unit8 ^ (key&7)]
    __shared__ unsigned short Vs[2][128 * 64];   // [d][key-unit8 ^ (d&7)]
    const int tid = threadIdx.x, lane = tid & 63, wid = tid >> 6;
    const int l31 = lane & 31, h2 = lane >> 5;
    const int lsw = l31 & 7;
    const int g8 = blockIdx.x & 7;               // (b,kvh) -> XCD pin
    const int b = g8 >> 2, kvh = g8 & 3;
    const int qi = 63 - (blockIdx.x >> 3);       // measured-best ordering
    const int h = kvh * 4 + wid;                 // wave = head
    const int qw = qi * 32;
    const int qq = qw + l31;                     // this lane's q row
    const size_t rs = 3072;

    const unsigned short* Qp = qkv + (size_t)(b * S + qw) * rs + h * 128 + h2 * 8;
    const unsigned short* Kbase = qkv + (size_t)(b * S) * rs + 2048 + kvh * 128;
    const unsigned short* Vtg = vtg + (size_t)((b * 4 + kvh) * 128) * S;

    // Q B-frag: col=q=l31, k = 16*kk + 8*h2 + e
    s8v qf[8];
#pragma unroll
    for (int kk = 0; kk < 8; ++kk)
        qf[kk] = *(const s8v*)(Qp + (size_t)l31 * rs + kk * 16);

    f32x16 acc[4] = {};                          // out^T: acc[dblk], row d, col q
    float m_run = -1e30f, l_run = 0.f;
    const int nt = (qi >> 1) + 1;

    auto stage = [&](int t, int bufi) {
        const int kb64 = t * 64;
#pragma unroll
        for (int i = 0; i < 4; ++i) {            // K tile [64][128]: 1024 chunks of 16B
            int c = i * 256 + tid;
            int key = c >> 4, d8 = c & 15;
            gload16(Kbase + (size_t)(kb64 + key) * rs + ((d8 ^ (key & 7)) << 3),
                    &Ks[bufi][(size_t)c * 8]);
        }
#pragma unroll
        for (int i = 0; i < 4; ++i) {            // V^T tile [128][64]
            int c = i * 256 + tid;
            int d = c >> 3, k8 = c & 7;
            gload16(Vtg + (size_t)d * S + kb64 + ((k8 ^ (d & 7)) << 3),
                    &Vs[bufi][(size_t)c * 8]);
        }
    };

    int cur = 0;
    stage(0, 0);
    __syncthreads();

    for (int t = 0; t < nt; ++t) {
        if (t + 1 < nt) stage(t + 1, cur ^ 1);
        const int kb64 = t * 64;
        const char* Kb = (const char*)&Ks[cur][0];
        const char* Vb = (const char*)&Vs[cur][0];

        // ---- K A-frags from LDS (row=key, k=16kk+8h2+e); conflict-free swizzled ----
        s8v kf0[8], kf1[8];
#pragma unroll
        for (int kk = 0; kk < 8; ++kk)
            kf0[kk] = *(const s8v*)(Kb + l31 * 256 + (((2 * kk + h2) ^ lsw) << 4));
#pragma unroll
        for (int kk = 0; kk < 8; ++kk)
            kf1[kk] = *(const s8v*)(Kb + (32 + l31) * 256 + (((2 * kk + h2) ^ lsw) << 4));
        // ---- V^T A-frags (row=d=32dblk+l31, k=key=16kb+8h2+e) ----
        s8v vf[4][4];
#pragma unroll
        for (int kb = 0; kb < 4; ++kb)
#pragma unroll
            for (int dblk = 0; dblk < 4; ++dblk)
                vf[kb][dblk] = *(const s8v*)(Vb + (32 * dblk + l31) * 128 +
                                             (((2 * kb + h2) ^ lsw) << 4));

        // ---- QK^T (swapped): S^T[key][q], C col = q lane-local ----
        f32x16 sacc0 = {}, sacc1 = {};
        __builtin_amdgcn_s_setprio(1);
#pragma unroll
        for (int kk = 0; kk < 8; ++kk)
            sacc0 = __builtin_amdgcn_mfma_f32_32x32x16_bf16(kf0[kk], qf[kk], sacc0, 0, 0, 0);
#pragma unroll
        for (int kk = 0; kk < 8; ++kk)
            sacc1 = __builtin_amdgcn_mfma_f32_32x32x16_bf16(kf1[kk], qf[kk], sacc1, 0, 0, 0);
        __builtin_amdgcn_s_setprio(0);

        // ---- scores (already log2-domain); mask only on the diagonal tile ----
        float sv[32];
        if (t == nt - 1) {
#pragma unroll
            for (int g = 0; g < 2; ++g)
#pragma unroll
                for (int r = 0; r < 16; ++r) {
                    int key = kb64 + 32 * g + (r & 3) + 8 * (r >> 2) + 4 * h2;
                    float s = (g ? sacc1[r] : sacc0[r]);
                    sv[g * 16 + r] = (key <= qq) ? s : -1e30f;
                }
        } else {
#pragma unroll
            for (int r = 0; r < 16; ++r) sv[r] = sacc0[r];
#pragma unroll
            for (int r = 0; r < 16; ++r) sv[16 + r] = sacc1[r];
        }

        // ---- online softmax (exp2 domain), q lane-local; defer-max THR=11.5 ----
        float mx = sv[0];
#pragma unroll
        for (int i = 1; i < 32; ++i) mx = fmaxf(mx, sv[i]);
        mx = fmaxf(mx, __shfl_xor(mx, 32));
        if (!__all(mx - m_run <= 11.5f)) {
            float mn = fmaxf(m_run, mx);
            float alpha = exp2f(m_run - mn);
            m_run = mn;
            l_run *= alpha;
#pragma unroll
            for (int dblk = 0; dblk < 4; ++dblk)
#pragma unroll
                for (int r = 0; r < 16; ++r) acc[dblk][r] *= alpha;
        }
        float ps = 0.f;
#pragma unroll
        for (int i = 0; i < 32; ++i) {
            float e = exp2f(sv[i] - m_run);
            sv[i] = e;
            ps += e;
        }
        ps += __shfl_xor(ps, 32);
        l_run += ps;

        // ---- P -> B-frag (col=q, k=key): cvt_pk pairs + lane^32 exchange ----
        unsigned int pw[4][4];
#pragma unroll
        for (int g = 0; g < 2; ++g) {
            unsigned int w[8];
#pragma unroll
            for (int j = 0; j < 8; ++j)
                w[j] = cvtpk(sv[g * 16 + 2 * j], sv[g * 16 + 2 * j + 1]);
#pragma unroll
            for (int u = 0; u < 2; ++u) {
                unsigned int t0 = (unsigned)__shfl_xor((int)w[4 * u + 0], 32);
                unsigned int t1 = (unsigned)__shfl_xor((int)w[4 * u + 1], 32);
                unsigned int t2 = (unsigned)__shfl_xor((int)w[4 * u + 2], 32);
                unsigned int t3 = (unsigned)__shfl_xor((int)w[4 * u + 3], 32);
                pw[2 * g + u][0] = h2 ? t2 : w[4 * u + 0];
                pw[2 * g + u][1] = h2 ? t3 : w[4 * u + 1];
                pw[2 * g + u][2] = h2 ? w[4 * u + 2] : t0;
                pw[2 * g + u][3] = h2 ? w[4 * u + 3] : t1;
            }
        }

        // ---- PV: out^T[d][q] += V^T(32d x 16k) * P^T(16k x 32q) ----
        __builtin_amdgcn_s_setprio(1);
#pragma unroll
        for (int kb = 0; kb < 4; ++kb) {
            u32x4 wv;
            wv[0] = pw[kb][0]; wv[1] = pw[kb][1]; wv[2] = pw[kb][2]; wv[3] = pw[kb][3];
            s8v pf = __builtin_bit_cast(s8v, wv);
#pragma unroll
            for (int dblk = 0; dblk < 4; ++dblk)
                acc[dblk] = __builtin_amdgcn_mfma_f32_32x32x16_bf16(vf[kb][dblk], pf, acc[dblk], 0, 0, 0);
        }
        __builtin_amdgcn_s_setprio(0);

        __syncthreads();
        cur ^= 1;
    }

    // ---- normalize (lane-local) and store out[q][h*128+d] ----
    float inv = 1.f / l_run;
    unsigned short* Op = out + (size_t)(b * S + qq) * 2048 + h * 128 + 4 * h2;
#pragma unroll
    for (int dblk = 0; dblk < 4; ++dblk)
#pragma unroll
        for (int s = 0; s < 4; ++s) {
            u32x2 wv;
            wv[0] = cvtpk(acc[dblk][4 * s + 0] * inv, acc[dblk][4 * s + 1] * inv);
            wv[1] = cvtpk(acc[dblk][4 * s + 2] * inv, acc[dblk][4 * s + 3] * inv);
            *(u32x2*)(Op + 32 * dblk + 8 * s) = wv;
        }
}

// ---------- launch ----------
extern "C" void kernel_launch(void* const* d_in, const int* in_sizes, int n_in,
                              void* d_out, int out_size, void* d_ws, size_t ws_size,
                              hipStream_t stream) {
    const float* x  = (const float*)d_in[0];
    const float* fc = (const float*)d_in[1];
    const float* fs = (const float*)d_in[2];
    const float* wq = (const float*)d_in[4];
    const float* wk = (const float*)d_in[5];
    const float* wv = (const float*)d_in[6];
    const float* wo = (const float*)d_in[7];
    float* out = (float*)d_out;

    char* ws = (char*)d_ws;
    unsigned short* xb    = (unsigned short*)ws;                               // 16 MB (reused as attn out)
    unsigned short* wqkvT = (unsigned short*)(ws + 16777216);                  // 12 MB (reused as V^T)
    unsigned short* woT   = (unsigned short*)(ws + 16777216 + 12582912);       // 8 MB
    unsigned short* qkvb  = (unsigned short*)(ws + 16777216 + 12582912 + 8388608); // 24 MB
    unsigned short* attnb = xb;
    unsigned short* vtb   = wqkvT;      // V^T [2][4][128][2048] = 4 MB, lives after gemm1

    prep_kernel<<<14336, 256, 0, stream>>>(x, wq, wk, wv, wo, xb, wqkvT, woT);
    gemm_bt<unsigned short><<<768, 256, 0, stream>>>(
        xb, wqkvT, qkvb, 4096, 3072, 2048, 3072);
    ropevt_kernel<<<7168, 256, 0, stream>>>(qkvb, fc, fs, vtb);
    attn_kernel<<<512, 256, 0, stream>>>(qkvb, vtb, attnb);
    gemm_bt<float><<<512, 256, 0, stream>>>(
        attnb, woT, out, 4096, 2048, 2048, 2048);
}

// Round 17
// 217.333 us; speedup vs baseline: 1.1779x; 1.0445x over previous
//
#include <hip/hip_runtime.h>
#include <type_traits>

// ---------- types ----------
typedef short s8v   __attribute__((ext_vector_type(8)));   // 8 x bf16 bits
typedef float f32x4 __attribute__((ext_vector_type(4)));
typedef float f32x16 __attribute__((ext_vector_type(16)));
typedef unsigned int u32x2 __attribute__((ext_vector_type(2)));
typedef unsigned int u32x4 __attribute__((ext_vector_type(4)));

__device__ __forceinline__ unsigned short f2bf(float f) {
    unsigned int u = __builtin_bit_cast(unsigned int, f);
    u += 0x7FFF + ((u >> 16) & 1);          // round-to-nearest-even
    return (unsigned short)(u >> 16);
}
__device__ __forceinline__ float bf2f(unsigned short b) {
    unsigned int u = ((unsigned int)b) << 16;
    return __builtin_bit_cast(float, u);
}
__device__ __forceinline__ unsigned int cvtpk(float lo, float hi) {
    unsigned int w;
    asm("v_cvt_pk_bf16_f32 %0, %1, %2" : "=v"(w) : "v"(lo), "v"(hi));
    return w;
}
// bare v_exp_f32: D = 2^S0 (R16 lesson: exp2f is a multi-inst libm call; __expf
// is v_mul+v_exp; this builtin is the single instruction).
__device__ __forceinline__ float exp2_hw(float x) {
    return __builtin_amdgcn_exp2f(x);
}

__device__ __forceinline__ void gload16(const void* g, void* l) {
    __builtin_amdgcn_global_load_lds(
        (const __attribute__((address_space(1))) void*)g,
        (__attribute__((address_space(3))) void*)l, 16, 0, 0);
}

// ---------- merged preprocessing: x->bf16 conv + wq/wk/wv transpose + wo transpose ----------
__global__ __launch_bounds__(256)
void prep_kernel(const float* __restrict__ x, const float* __restrict__ wq,
                 const float* __restrict__ wk, const float* __restrict__ wv,
                 const float* __restrict__ wo,
                 unsigned short* __restrict__ xb, unsigned short* __restrict__ wqkvT,
                 unsigned short* __restrict__ woT) {
    __shared__ float tile[32][33];
    const int bid = blockIdx.x;
    if (bid < 4096) {
        int i = bid * 256 + threadIdx.x;
        const f32x4* s4 = (const f32x4*)x;
        f32x4 a = s4[2 * i], b = s4[2 * i + 1];
        s8v o;
        o[0] = (short)f2bf(a[0]); o[1] = (short)f2bf(a[1]);
        o[2] = (short)f2bf(a[2]); o[3] = (short)f2bf(a[3]);
        o[4] = (short)f2bf(b[0]); o[5] = (short)f2bf(b[1]);
        o[6] = (short)f2bf(b[2]); o[7] = (short)f2bf(b[3]);
        *(s8v*)(xb + (size_t)i * 8) = o;
        return;
    }
    const int tx = threadIdx.x & 31, ty = threadIdx.x >> 5;
    const float* src; unsigned short* dst; int sc, N, n0, k0;
    if (bid < 10240) {
        int lb = bid - 4096;
        n0 = (lb % 96) * 32; k0 = (lb / 96) * 32;
        if (n0 < 2048)      { src = wq; sc = n0;        N = 2048; }
        else if (n0 < 2560) { src = wk; sc = n0 - 2048; N = 512;  }
        else                { src = wv; sc = n0 - 2560; N = 512;  }
        dst = wqkvT;
    } else {
        int lb = bid - 10240;
        n0 = (lb % 64) * 32; k0 = (lb / 64) * 32;
        src = wo; sc = n0; N = 2048; dst = woT;
    }
#pragma unroll
    for (int r = 0; r < 4; ++r)
        tile[ty + r * 8][tx] = src[(size_t)(k0 + ty + r * 8) * N + sc + tx];
    __syncthreads();
#pragma unroll
    for (int r = 0; r < 4; ++r)
        dst[(size_t)(n0 + ty + r * 8) * 2048 + k0 + tx] = f2bf(tile[tx][ty + r * 8]);
}

// ---------- RoPE (+q scale*log2e fold) and V->V^T, one launch ----------
// blocks [0,5120): rope in-place on qkvb; q cols get rope * (1/sqrt(128) * log2(e))
//   so attention scores are directly in log2 domain.
// blocks [5120,7168): vtrans of V cols -> vt [b][kvh][128][2048]
__global__ __launch_bounds__(256)
void ropevt_kernel(unsigned short* __restrict__ qkv, const float* __restrict__ fc,
                   const float* __restrict__ fs, unsigned short* __restrict__ vt) {
    __shared__ unsigned short t[32][33];
    const int bid = blockIdx.x;
    if (bid < 5120) {
        int idx = bid * 256 + threadIdx.x;
        int grp = idx & 15;
        int hh = (idx >> 4) % 20;
        int row = idx / (16 * 20);
        int s = row & 2047;
        int col0 = (hh < 16 ? hh * 128 : 2048 + (hh - 16) * 128) + grp * 8;
        unsigned short* p = qkv + (size_t)row * 3072 + col0;
        s8v v = *(const s8v*)p;
        const float* cc = fc + (size_t)s * 64 + grp * 4;
        const float* ss = fs + (size_t)s * 64 + grp * 4;
        const float sc = (hh < 16) ? (0.08838834764831845f * 1.4426950408889634f) : 1.0f;
#pragma unroll
        for (int j = 0; j < 4; ++j) {
            float xe = bf2f((unsigned short)v[2 * j]);
            float xo = bf2f((unsigned short)v[2 * j + 1]);
            float c = cc[j], sn = ss[j];
            v[2 * j]     = (short)f2bf((xe * c - xo * sn) * sc);
            v[2 * j + 1] = (short)f2bf((xe * sn + xo * c) * sc);
        }
        *(s8v*)p = v;
        return;
    }
    int vb = bid - 5120;               // 0..2047
    int s0 = (vb & 127) * 32, c0 = (vb >> 7) * 32;
    int tx = threadIdx.x & 31, ty = threadIdx.x >> 5;
#pragma unroll
    for (int r = 0; r < 4; ++r)
        t[ty + r * 8][tx] = qkv[(size_t)(s0 + ty + r * 8) * 3072 + 2560 + c0 + tx];
    __syncthreads();
    int b = s0 >> 11, s = s0 & 2047;
    size_t dbase = (size_t)(b * 4 + (c0 >> 7)) * 128 + (c0 & 127);
#pragma unroll
    for (int r = 0; r < 4; ++r)
        vt[(dbase + ty + r * 8) * 2048 + s + tx] = t[tx][ty + r * 8];
}

// ---------- GEMM (R14 kernel, unchanged — measured good): C = A(MxK) * B^T(NxK) ----------
template <typename CT>
__global__ __launch_bounds__(256)
void gemm_bt(const unsigned short* __restrict__ A, const unsigned short* __restrict__ BT,
             CT* __restrict__ C, int M, int N, int K, int ldc) {
    __shared__ unsigned short As[128 * 64];
    __shared__ unsigned short Bs[128 * 64];
    const int tid = threadIdx.x;
    const int wid = tid >> 6, lane = tid & 63;
    const int l31 = lane & 31, h2 = lane >> 5;
    const int nbx = N >> 7;
    const int per = nbx >> 3;
    const int xcd = blockIdx.x & 7;
    const int li  = blockIdx.x >> 3;
    const int bx  = xcd * per + (li % per);
    const int by  = li / per;
    const int brow = by * 128, bcol = bx * 128;
    const int wr = wid >> 1, wc = wid & 1;
    f32x16 acc[2][2] = {};

    for (int kt = 0; kt < K; kt += 64) {
#pragma unroll
        for (int i = 0; i < 4; ++i) {
            int c = i * 256 + tid;
            int row = c >> 3, u = c & 7;
            gload16(A + (size_t)(brow + row) * K + kt + ((u ^ (row & 7)) << 3),
                    As + (size_t)c * 8);
            gload16(BT + (size_t)(bcol + row) * K + kt + ((u ^ (row & 7)) << 3),
                    Bs + (size_t)c * 8);
        }
        __syncthreads();
        s8v a[2][4], b[2][4];
#pragma unroll
        for (int mm = 0; mm < 2; ++mm) {
            int row = wr * 64 + mm * 32 + l31;
#pragma unroll
            for (int ks = 0; ks < 4; ++ks)
                a[mm][ks] = *(const s8v*)(As + (size_t)row * 64 +
                                          (((2 * ks + h2) ^ (row & 7)) << 3));
        }
#pragma unroll
        for (int nn = 0; nn < 2; ++nn) {
            int row = wc * 64 + nn * 32 + l31;
#pragma unroll
            for (int ks = 0; ks < 4; ++ks)
                b[nn][ks] = *(const s8v*)(Bs + (size_t)row * 64 +
                                          (((2 * ks + h2) ^ (row & 7)) << 3));
        }
#pragma unroll
        for (int ks = 0; ks < 4; ++ks)
#pragma unroll
            for (int mm = 0; mm < 2; ++mm)
#pragma unroll
                for (int nn = 0; nn < 2; ++nn)
                    acc[mm][nn] = __builtin_amdgcn_mfma_f32_32x32x16_bf16(
                        a[mm][ks], b[nn][ks], acc[mm][nn], 0, 0, 0);
        __syncthreads();
    }
#pragma unroll
    for (int mm = 0; mm < 2; ++mm)
#pragma unroll
        for (int nn = 0; nn < 2; ++nn)
#pragma unroll
            for (int reg = 0; reg < 16; ++reg) {
                int r = brow + wr * 64 + mm * 32 + (reg & 3) + 8 * (reg >> 2) + 4 * h2;
                int c = bcol + wc * 64 + nn * 32 + l31;
                float v = acc[mm][nn][reg];
                if constexpr (std::is_same<CT, float>::value)
                    C[(size_t)r * ldc + c] = v;
                else
                    C[(size_t)r * ldc + c] = f2bf(v);
            }
}

// ---------- Flash attention (R14 structure) + exp2 softmax via bare v_exp_f32 ----------
// 512 blocks x 256 threads (4 waves = 4 heads of one kvh). blockIdx&7 = (b,kvh).
// qi = 63 - (bid>>3): measured-best. Balance experiments PARKED (R7/R9/R15).
// Scores arrive pre-scaled by 1/sqrt(128)*log2e (rope fold) -> softmax uses
// __builtin_amdgcn_exp2f (single v_exp_f32; R16's exp2f libm call regressed).
// defer-max THR=11.5 (=8*log2e). Mask only on the diagonal tile.
__global__ __launch_bounds__(256)
void attn_kernel(const unsigned short* __restrict__ qkv,
                 const unsigned short* __restrict__ vtg,
                 unsigned short* __restrict__ out) {
    constexpr int S = 2048;
    __shared__ unsigned short Ks[2][64 * 128];   // [key][d-unit8 ^ (key&7)]
    __shared__ unsigned short Vs[2][128 * 64];   // [d][key-unit8 ^ (d&7)]
    const int tid = threadIdx.x, lane = tid & 63, wid = tid >> 6;
    const int l31 = lane & 31, h2 = lane >> 5;
    const int lsw = l31 & 7;
    const int g8 = blockIdx.x & 7;               // (b,kvh) -> XCD pin
    const int b = g8 >> 2, kvh = g8 & 3;
    const int qi = 63 - (blockIdx.x >> 3);       // measured-best ordering
    const int h = kvh * 4 + wid;                 // wave = head
    const int qw = qi * 32;
    const int qq = qw + l31;                     // this lane's q row
    const size_t rs = 3072;

    const unsigned short* Qp = qkv + (size_t)(b * S + qw) * rs + h * 128 + h2 * 8;
    const unsigned short* Kbase = qkv + (size_t)(b * S) * rs + 2048 + kvh * 128;
    const unsigned short* Vtg = vtg + (size_t)((b * 4 + kvh) * 128) * S;

    // Q B-frag: col=q=l31, k = 16*kk + 8*h2 + e
    s8v qf[8];
#pragma unroll
    for (int kk = 0; kk < 8; ++kk)
        qf[kk] = *(const s8v*)(Qp + (size_t)l31 * rs + kk * 16);

    f32x16 acc[4] = {};                          // out^T: acc[dblk], row d, col q
    float m_run = -1e30f, l_run = 0.f;
    const int nt = (qi >> 1) + 1;

    auto stage = [&](int t, int bufi) {
        const int kb64 = t * 64;
#pragma unroll
        for (int i = 0; i < 4; ++i) {            // K tile [64][128]: 1024 chunks of 16B
            int c = i * 256 + tid;
            int key = c >> 4, d8 = c & 15;
            gload16(Kbase + (size_t)(kb64 + key) * rs + ((d8 ^ (key & 7)) << 3),
                    &Ks[bufi][(size_t)c * 8]);
        }
#pragma unroll
        for (int i = 0; i < 4; ++i) {            // V^T tile [128][64]
            int c = i * 256 + tid;
            int d = c >> 3, k8 = c & 7;
            gload16(Vtg + (size_t)d * S + kb64 + ((k8 ^ (d & 7)) << 3),
                    &Vs[bufi][(size_t)c * 8]);
        }
    };

    int cur = 0;
    stage(0, 0);
    __syncthreads();

    for (int t = 0; t < nt; ++t) {
        if (t + 1 < nt) stage(t + 1, cur ^ 1);
        const int kb64 = t * 64;
        const char* Kb = (const char*)&Ks[cur][0];
        const char* Vb = (const char*)&Vs[cur][0];

        // ---- K A-frags from LDS (row=key, k=16kk+8h2+e); conflict-free swizzled ----
        s8v kf0[8], kf1[8];
#pragma unroll
        for (int kk = 0; kk < 8; ++kk)
            kf0[kk] = *(const s8v*)(Kb + l31 * 256 + (((2 * kk + h2) ^ lsw) << 4));
#pragma unroll
        for (int kk = 0; kk < 8; ++kk)
            kf1[kk] = *(const s8v*)(Kb + (32 + l31) * 256 + (((2 * kk + h2) ^ lsw) << 4));
        // ---- V^T A-frags (row=d=32dblk+l31, k=key=16kb+8h2+e) ----
        s8v vf[4][4];
#pragma unroll
        for (int kb = 0; kb < 4; ++kb)
#pragma unroll
            for (int dblk = 0; dblk < 4; ++dblk)
                vf[kb][dblk] = *(const s8v*)(Vb + (32 * dblk + l31) * 128 +
                                             (((2 * kb + h2) ^ lsw) << 4));

        // ---- QK^T (swapped): S^T[key][q], C col = q lane-local ----
        f32x16 sacc0 = {}, sacc1 = {};
        __builtin_amdgcn_s_setprio(1);
#pragma unroll
        for (int kk = 0; kk < 8; ++kk)
            sacc0 = __builtin_amdgcn_mfma_f32_32x32x16_bf16(kf0[kk], qf[kk], sacc0, 0, 0, 0);
#pragma unroll
        for (int kk = 0; kk < 8; ++kk)
            sacc1 = __builtin_amdgcn_mfma_f32_32x32x16_bf16(kf1[kk], qf[kk], sacc1, 0, 0, 0);
        __builtin_amdgcn_s_setprio(0);

        // ---- scores (already log2-domain); mask only on the diagonal tile ----
        float sv[32];
        if (t == nt - 1) {
#pragma unroll
            for (int g = 0; g < 2; ++g)
#pragma unroll
                for (int r = 0; r < 16; ++r) {
                    int key = kb64 + 32 * g + (r & 3) + 8 * (r >> 2) + 4 * h2;
                    float s = (g ? sacc1[r] : sacc0[r]);
                    sv[g * 16 + r] = (key <= qq) ? s : -1e30f;
                }
        } else {
#pragma unroll
            for (int r = 0; r < 16; ++r) sv[r] = sacc0[r];
#pragma unroll
            for (int r = 0; r < 16; ++r) sv[16 + r] = sacc1[r];
        }

        // ---- online softmax (exp2 domain, bare v_exp_f32); defer-max THR=11.5 ----
        float mx = sv[0];
#pragma unroll
        for (int i = 1; i < 32; ++i) mx = fmaxf(mx, sv[i]);
        mx = fmaxf(mx, __shfl_xor(mx, 32));
        if (!__all(mx - m_run <= 11.5f)) {
            float mn = fmaxf(m_run, mx);
            float alpha = exp2_hw(m_run - mn);
            m_run = mn;
            l_run *= alpha;
#pragma unroll
            for (int dblk = 0; dblk < 4; ++dblk)
#pragma unroll
                for (int r = 0; r < 16; ++r) acc[dblk][r] *= alpha;
        }
        float ps = 0.f;
#pragma unroll
        for (int i = 0; i < 32; ++i) {
            float e = exp2_hw(sv[i] - m_run);
            sv[i] = e;
            ps += e;
        }
        ps += __shfl_xor(ps, 32);
        l_run += ps;

        // ---- P -> B-frag (col=q, k=key): cvt_pk pairs + lane^32 exchange ----
        unsigned int pw[4][4];
#pragma unroll
        for (int g = 0; g < 2; ++g) {
            unsigned int w[8];
#pragma unroll
            for (int j = 0; j < 8; ++j)
                w[j] = cvtpk(sv[g * 16 + 2 * j], sv[g * 16 + 2 * j + 1]);
#pragma unroll
            for (int u = 0; u < 2; ++u) {
                unsigned int t0 = (unsigned)__shfl_xor((int)w[4 * u + 0], 32);
                unsigned int t1 = (unsigned)__shfl_xor((int)w[4 * u + 1], 32);
                unsigned int t2 = (unsigned)__shfl_xor((int)w[4 * u + 2], 32);
                unsigned int t3 = (unsigned)__shfl_xor((int)w[4 * u + 3], 32);
                pw[2 * g + u][0] = h2 ? t2 : w[4 * u + 0];
                pw[2 * g + u][1] = h2 ? t3 : w[4 * u + 1];
                pw[2 * g + u][2] = h2 ? w[4 * u + 2] : t0;
                pw[2 * g + u][3] = h2 ? w[4 * u + 3] : t1;
            }
        }

        // ---- PV: out^T[d][q] += V^T(32d x 16k) * P^T(16k x 32q) ----
        __builtin_amdgcn_s_setprio(1);
#pragma unroll
        for (int kb = 0; kb < 4; ++kb) {
            u32x4 wv;
            wv[0] = pw[kb][0]; wv[1] = pw[kb][1]; wv[2] = pw[kb][2]; wv[3] = pw[kb][3];
            s8v pf = __builtin_bit_cast(s8v, wv);
#pragma unroll
            for (int dblk = 0; dblk < 4; ++dblk)
                acc[dblk] = __builtin_amdgcn_mfma_f32_32x32x16_bf16(vf[kb][dblk], pf, acc[dblk], 0, 0, 0);
        }
        __builtin_amdgcn_s_setprio(0);

        __syncthreads();
        cur ^= 1;
    }

    // ---- normalize (lane-local) and store out[q][h*128+d] ----
    float inv = 1.f / l_run;
    unsigned short* Op = out + (size_t)(b * S + qq) * 2048 + h * 128 + 4 * h2;
#pragma unroll
    for (int dblk = 0; dblk < 4; ++dblk)
#pragma unroll
        for (int s = 0; s < 4; ++s) {
            u32x2 wv;
            wv[0] = cvtpk(acc[dblk][4 * s + 0] * inv, acc[dblk][4 * s + 1] * inv);
            wv[1] = cvtpk(acc[dblk][4 * s + 2] * inv, acc[dblk][4 * s + 3] * inv);
            *(u32x2*)(Op + 32 * dblk + 8 * s) = wv;
        }
}

// ---------- launch ----------
extern "C" void kernel_launch(void* const* d_in, const int* in_sizes, int n_in,
                              void* d_out, int out_size, void* d_ws, size_t ws_size,
                              hipStream_t stream) {
    const float* x  = (const float*)d_in[0];
    const float* fc = (const float*)d_in[1];
    const float* fs = (const float*)d_in[2];
    const float* wq = (const float*)d_in[4];
    const float* wk = (const float*)d_in[5];
    const float* wv = (const float*)d_in[6];
    const float* wo = (const float*)d_in[7];
    float* out = (float*)d_out;

    char* ws = (char*)d_ws;
    unsigned short* xb    = (unsigned short*)ws;                               // 16 MB (reused as attn out)
    unsigned short* wqkvT = (unsigned short*)(ws + 16777216);                  // 12 MB (reused as V^T)
    unsigned short* woT   = (unsigned short*)(ws + 16777216 + 12582912);       // 8 MB
    unsigned short* qkvb  = (unsigned short*)(ws + 16777216 + 12582912 + 8388608); // 24 MB
    unsigned short* attnb = xb;
    unsigned short* vtb   = wqkvT;      // V^T [2][4][128][2048] = 4 MB, lives after gemm1

    prep_kernel<<<14336, 256, 0, stream>>>(x, wq, wk, wv, wo, xb, wqkvT, woT);
    gemm_bt<unsigned short><<<768, 256, 0, stream>>>(
        xb, wqkvT, qkvb, 4096, 3072, 2048, 3072);
    ropevt_kernel<<<7168, 256, 0, stream>>>(qkvb, fc, fs, vtb);
    attn_kernel<<<512, 256, 0, stream>>>(qkvb, vtb, attnb);
    gemm_bt<float><<<512, 256, 0, stream>>>(
        attnb, woT, out, 4096, 2048, 2048, 2048);
}

// Round 18
// 217.193 us; speedup vs baseline: 1.1786x; 1.0006x over previous
//
#include <hip/hip_runtime.h>
#include <type_traits>

// ---------- types ----------
typedef short s8v   __attribute__((ext_vector_type(8)));   // 8 x bf16 bits
typedef float f32x4 __attribute__((ext_vector_type(4)));
typedef float f32x16 __attribute__((ext_vector_type(16)));
typedef unsigned int u32x2 __attribute__((ext_vector_type(2)));
typedef unsigned int u32x4 __attribute__((ext_vector_type(4)));

__device__ __forceinline__ unsigned short f2bf(float f) {
    unsigned int u = __builtin_bit_cast(unsigned int, f);
    u += 0x7FFF + ((u >> 16) & 1);          // round-to-nearest-even
    return (unsigned short)(u >> 16);
}
__device__ __forceinline__ float bf2f(unsigned short b) {
    unsigned int u = ((unsigned int)b) << 16;
    return __builtin_bit_cast(float, u);
}
__device__ __forceinline__ unsigned int cvtpk(float lo, float hi) {
    unsigned int w;
    asm("v_cvt_pk_bf16_f32 %0, %1, %2" : "=v"(w) : "v"(lo), "v"(hi));
    return w;
}
// bare v_exp_f32: D = 2^S0 (R16/R17 lesson: exp2f = libm multi-inst; __expf = mul+exp).
__device__ __forceinline__ float exp2_hw(float x) {
    return __builtin_amdgcn_exp2f(x);
}

__device__ __forceinline__ void gload16(const void* g, void* l) {
    __builtin_amdgcn_global_load_lds(
        (const __attribute__((address_space(1))) void*)g,
        (__attribute__((address_space(3))) void*)l, 16, 0, 0);
}

// ---------- merged preprocessing: x->bf16 conv + wq/wk/wv transpose + wo transpose ----------
__global__ __launch_bounds__(256)
void prep_kernel(const float* __restrict__ x, const float* __restrict__ wq,
                 const float* __restrict__ wk, const float* __restrict__ wv,
                 const float* __restrict__ wo,
                 unsigned short* __restrict__ xb, unsigned short* __restrict__ wqkvT,
                 unsigned short* __restrict__ woT) {
    __shared__ float tile[32][33];
    const int bid = blockIdx.x;
    if (bid < 4096) {
        int i = bid * 256 + threadIdx.x;
        const f32x4* s4 = (const f32x4*)x;
        f32x4 a = s4[2 * i], b = s4[2 * i + 1];
        s8v o;
        o[0] = (short)f2bf(a[0]); o[1] = (short)f2bf(a[1]);
        o[2] = (short)f2bf(a[2]); o[3] = (short)f2bf(a[3]);
        o[4] = (short)f2bf(b[0]); o[5] = (short)f2bf(b[1]);
        o[6] = (short)f2bf(b[2]); o[7] = (short)f2bf(b[3]);
        *(s8v*)(xb + (size_t)i * 8) = o;
        return;
    }
    const int tx = threadIdx.x & 31, ty = threadIdx.x >> 5;
    const float* src; unsigned short* dst; int sc, N, n0, k0;
    if (bid < 10240) {
        int lb = bid - 4096;
        n0 = (lb % 96) * 32; k0 = (lb / 96) * 32;
        if (n0 < 2048)      { src = wq; sc = n0;        N = 2048; }
        else if (n0 < 2560) { src = wk; sc = n0 - 2048; N = 512;  }
        else                { src = wv; sc = n0 - 2560; N = 512;  }
        dst = wqkvT;
    } else {
        int lb = bid - 10240;
        n0 = (lb % 64) * 32; k0 = (lb / 64) * 32;
        src = wo; sc = n0; N = 2048; dst = woT;
    }
#pragma unroll
    for (int r = 0; r < 4; ++r)
        tile[ty + r * 8][tx] = src[(size_t)(k0 + ty + r * 8) * N + sc + tx];
    __syncthreads();
#pragma unroll
    for (int r = 0; r < 4; ++r)
        dst[(size_t)(n0 + ty + r * 8) * 2048 + k0 + tx] = f2bf(tile[tx][ty + r * 8]);
}

// ---------- RoPE (+q scale*log2e fold) and V->V^T, one launch ----------
__global__ __launch_bounds__(256)
void ropevt_kernel(unsigned short* __restrict__ qkv, const float* __restrict__ fc,
                   const float* __restrict__ fs, unsigned short* __restrict__ vt) {
    __shared__ unsigned short t[32][33];
    const int bid = blockIdx.x;
    if (bid < 5120) {
        int idx = bid * 256 + threadIdx.x;
        int grp = idx & 15;
        int hh = (idx >> 4) % 20;
        int row = idx / (16 * 20);
        int s = row & 2047;
        int col0 = (hh < 16 ? hh * 128 : 2048 + (hh - 16) * 128) + grp * 8;
        unsigned short* p = qkv + (size_t)row * 3072 + col0;
        s8v v = *(const s8v*)p;
        const float* cc = fc + (size_t)s * 64 + grp * 4;
        const float* ss = fs + (size_t)s * 64 + grp * 4;
        const float sc = (hh < 16) ? (0.08838834764831845f * 1.4426950408889634f) : 1.0f;
#pragma unroll
        for (int j = 0; j < 4; ++j) {
            float xe = bf2f((unsigned short)v[2 * j]);
            float xo = bf2f((unsigned short)v[2 * j + 1]);
            float c = cc[j], sn = ss[j];
            v[2 * j]     = (short)f2bf((xe * c - xo * sn) * sc);
            v[2 * j + 1] = (short)f2bf((xe * sn + xo * c) * sc);
        }
        *(s8v*)p = v;
        return;
    }
    int vb = bid - 5120;               // 0..2047
    int s0 = (vb & 127) * 32, c0 = (vb >> 7) * 32;
    int tx = threadIdx.x & 31, ty = threadIdx.x >> 5;
#pragma unroll
    for (int r = 0; r < 4; ++r)
        t[ty + r * 8][tx] = qkv[(size_t)(s0 + ty + r * 8) * 3072 + 2560 + c0 + tx];
    __syncthreads();
    int b = s0 >> 11, s = s0 & 2047;
    size_t dbase = (size_t)(b * 4 + (c0 >> 7)) * 128 + (c0 & 127);
#pragma unroll
    for (int r = 0; r < 4; ++r)
        vt[(dbase + ty + r * 8) * 2048 + s + tx] = t[tx][ty + r * 8];
}

// ---------- GEMM (R14 kernel, unchanged — measured good): C = A(MxK) * B^T(NxK) ----------
template <typename CT>
__global__ __launch_bounds__(256)
void gemm_bt(const unsigned short* __restrict__ A, const unsigned short* __restrict__ BT,
             CT* __restrict__ C, int M, int N, int K, int ldc) {
    __shared__ unsigned short As[128 * 64];
    __shared__ unsigned short Bs[128 * 64];
    const int tid = threadIdx.x;
    const int wid = tid >> 6, lane = tid & 63;
    const int l31 = lane & 31, h2 = lane >> 5;
    const int nbx = N >> 7;
    const int per = nbx >> 3;
    const int xcd = blockIdx.x & 7;
    const int li  = blockIdx.x >> 3;
    const int bx  = xcd * per + (li % per);
    const int by  = li / per;
    const int brow = by * 128, bcol = bx * 128;
    const int wr = wid >> 1, wc = wid & 1;
    f32x16 acc[2][2] = {};

    for (int kt = 0; kt < K; kt += 64) {
#pragma unroll
        for (int i = 0; i < 4; ++i) {
            int c = i * 256 + tid;
            int row = c >> 3, u = c & 7;
            gload16(A + (size_t)(brow + row) * K + kt + ((u ^ (row & 7)) << 3),
                    As + (size_t)c * 8);
            gload16(BT + (size_t)(bcol + row) * K + kt + ((u ^ (row & 7)) << 3),
                    Bs + (size_t)c * 8);
        }
        __syncthreads();
        s8v a[2][4], b[2][4];
#pragma unroll
        for (int mm = 0; mm < 2; ++mm) {
            int row = wr * 64 + mm * 32 + l31;
#pragma unroll
            for (int ks = 0; ks < 4; ++ks)
                a[mm][ks] = *(const s8v*)(As + (size_t)row * 64 +
                                          (((2 * ks + h2) ^ (row & 7)) << 3));
        }
#pragma unroll
        for (int nn = 0; nn < 2; ++nn) {
            int row = wc * 64 + nn * 32 + l31;
#pragma unroll
            for (int ks = 0; ks < 4; ++ks)
                b[nn][ks] = *(const s8v*)(Bs + (size_t)row * 64 +
                                          (((2 * ks + h2) ^ (row & 7)) << 3));
        }
#pragma unroll
        for (int ks = 0; ks < 4; ++ks)
#pragma unroll
            for (int mm = 0; mm < 2; ++mm)
#pragma unroll
                for (int nn = 0; nn < 2; ++nn)
                    acc[mm][nn] = __builtin_amdgcn_mfma_f32_32x32x16_bf16(
                        a[mm][ks], b[nn][ks], acc[mm][nn], 0, 0, 0);
        __syncthreads();
    }
#pragma unroll
    for (int mm = 0; mm < 2; ++mm)
#pragma unroll
        for (int nn = 0; nn < 2; ++nn)
#pragma unroll
            for (int reg = 0; reg < 16; ++reg) {
                int r = brow + wr * 64 + mm * 32 + (reg & 3) + 8 * (reg >> 2) + 4 * h2;
                int c = bcol + wc * 64 + nn * 32 + l31;
                float v = acc[mm][nn][reg];
                if constexpr (std::is_same<CT, float>::value)
                    C[(size_t)r * ldc + c] = v;
                else
                    C[(size_t)r * ldc + c] = f2bf(v);
            }
}

// ---------- Flash attention (R17 structure) + tree reductions ----------
// 512 blocks x 256 threads (4 waves = 4 heads of one kvh). blockIdx&7 = (b,kvh).
// qi = 63 - (bid>>3): measured-best. Balance experiments PARKED (R7/R9/R15).
// Scores pre-scaled by 1/sqrt(128)*log2e (rope fold); softmax = bare v_exp_f32.
// R18: max/sum reductions restructured as depth-5 trees (were 31/32-deep serial
// chains = ~250 stall cycles/tile/wave; both pipes idle in PMC -> dependency-bound).
__global__ __launch_bounds__(256)
void attn_kernel(const unsigned short* __restrict__ qkv,
                 const unsigned short* __restrict__ vtg,
                 unsigned short* __restrict__ out) {
    constexpr int S = 2048;
    __shared__ unsigned short Ks[2][64 * 128];   // [key][d-unit8 ^ (key&7)]
    __shared__ unsigned short Vs[2][128 * 64];   // [d][key-unit8 ^ (d&7)]
    const int tid = threadIdx.x, lane = tid & 63, wid = tid >> 6;
    const int l31 = lane & 31, h2 = lane >> 5;
    const int lsw = l31 & 7;
    const int g8 = blockIdx.x & 7;               // (b,kvh) -> XCD pin
    const int b = g8 >> 2, kvh = g8 & 3;
    const int qi = 63 - (blockIdx.x >> 3);       // measured-best ordering
    const int h = kvh * 4 + wid;                 // wave = head
    const int qw = qi * 32;
    const int qq = qw + l31;                     // this lane's q row
    const size_t rs = 3072;

    const unsigned short* Qp = qkv + (size_t)(b * S + qw) * rs + h * 128 + h2 * 8;
    const unsigned short* Kbase = qkv + (size_t)(b * S) * rs + 2048 + kvh * 128;
    const unsigned short* Vtg = vtg + (size_t)((b * 4 + kvh) * 128) * S;

    // Q B-frag: col=q=l31, k = 16*kk + 8*h2 + e
    s8v qf[8];
#pragma unroll
    for (int kk = 0; kk < 8; ++kk)
        qf[kk] = *(const s8v*)(Qp + (size_t)l31 * rs + kk * 16);

    f32x16 acc[4] = {};                          // out^T: acc[dblk], row d, col q
    float m_run = -1e30f, l_run = 0.f;
    const int nt = (qi >> 1) + 1;

    auto stage = [&](int t, int bufi) {
        const int kb64 = t * 64;
#pragma unroll
        for (int i = 0; i < 4; ++i) {            // K tile [64][128]: 1024 chunks of 16B
            int c = i * 256 + tid;
            int key = c >> 4, d8 = c & 15;
            gload16(Kbase + (size_t)(kb64 + key) * rs + ((d8 ^ (key & 7)) << 3),
                    &Ks[bufi][(size_t)c * 8]);
        }
#pragma unroll
        for (int i = 0; i < 4; ++i) {            // V^T tile [128][64]
            int c = i * 256 + tid;
            int d = c >> 3, k8 = c & 7;
            gload16(Vtg + (size_t)d * S + kb64 + ((k8 ^ (d & 7)) << 3),
                    &Vs[bufi][(size_t)c * 8]);
        }
    };

    int cur = 0;
    stage(0, 0);
    __syncthreads();

    for (int t = 0; t < nt; ++t) {
        if (t + 1 < nt) stage(t + 1, cur ^ 1);
        const int kb64 = t * 64;
        const char* Kb = (const char*)&Ks[cur][0];
        const char* Vb = (const char*)&Vs[cur][0];

        // ---- K A-frags from LDS (row=key, k=16kk+8h2+e); conflict-free swizzled ----
        s8v kf0[8], kf1[8];
#pragma unroll
        for (int kk = 0; kk < 8; ++kk)
            kf0[kk] = *(const s8v*)(Kb + l31 * 256 + (((2 * kk + h2) ^ lsw) << 4));
#pragma unroll
        for (int kk = 0; kk < 8; ++kk)
            kf1[kk] = *(const s8v*)(Kb + (32 + l31) * 256 + (((2 * kk + h2) ^ lsw) << 4));
        // ---- V^T A-frags (row=d=32dblk+l31, k=key=16kb+8h2+e) ----
        s8v vf[4][4];
#pragma unroll
        for (int kb = 0; kb < 4; ++kb)
#pragma unroll
            for (int dblk = 0; dblk < 4; ++dblk)
                vf[kb][dblk] = *(const s8v*)(Vb + (32 * dblk + l31) * 128 +
                                             (((2 * kb + h2) ^ lsw) << 4));

        // ---- QK^T (swapped): S^T[key][q], C col = q lane-local ----
        f32x16 sacc0 = {}, sacc1 = {};
        __builtin_amdgcn_s_setprio(1);
#pragma unroll
        for (int kk = 0; kk < 8; ++kk)
            sacc0 = __builtin_amdgcn_mfma_f32_32x32x16_bf16(kf0[kk], qf[kk], sacc0, 0, 0, 0);
#pragma unroll
        for (int kk = 0; kk < 8; ++kk)
            sacc1 = __builtin_amdgcn_mfma_f32_32x32x16_bf16(kf1[kk], qf[kk], sacc1, 0, 0, 0);
        __builtin_amdgcn_s_setprio(0);

        // ---- scores (already log2-domain); mask only on the diagonal tile ----
        float sv[32];
        if (t == nt - 1) {
#pragma unroll
            for (int g = 0; g < 2; ++g)
#pragma unroll
                for (int r = 0; r < 16; ++r) {
                    int key = kb64 + 32 * g + (r & 3) + 8 * (r >> 2) + 4 * h2;
                    float s = (g ? sacc1[r] : sacc0[r]);
                    sv[g * 16 + r] = (key <= qq) ? s : -1e30f;
                }
        } else {
#pragma unroll
            for (int r = 0; r < 16; ++r) sv[r] = sacc0[r];
#pragma unroll
            for (int r = 0; r < 16; ++r) sv[16 + r] = sacc1[r];
        }

        // ---- online softmax (exp2 domain); TREE reductions (depth 5, was 32) ----
        float m8[8];
#pragma unroll
        for (int i = 0; i < 8; ++i)
            m8[i] = fmaxf(fmaxf(sv[4 * i], sv[4 * i + 1]),
                          fmaxf(sv[4 * i + 2], sv[4 * i + 3]));
        float mA = fmaxf(fmaxf(m8[0], m8[1]), fmaxf(m8[2], m8[3]));
        float mB = fmaxf(fmaxf(m8[4], m8[5]), fmaxf(m8[6], m8[7]));
        float mx = fmaxf(mA, mB);
        mx = fmaxf(mx, __shfl_xor(mx, 32));
        if (!__all(mx - m_run <= 11.5f)) {
            float mn = fmaxf(m_run, mx);
            float alpha = exp2_hw(m_run - mn);
            m_run = mn;
            l_run *= alpha;
#pragma unroll
            for (int dblk = 0; dblk < 4; ++dblk)
#pragma unroll
                for (int r = 0; r < 16; ++r) acc[dblk][r] *= alpha;
        }
#pragma unroll
        for (int i = 0; i < 32; ++i)
            sv[i] = exp2_hw(sv[i] - m_run);
        float s8a[8];
#pragma unroll
        for (int i = 0; i < 8; ++i)
            s8a[i] = (sv[4 * i] + sv[4 * i + 1]) + (sv[4 * i + 2] + sv[4 * i + 3]);
        float sA = (s8a[0] + s8a[1]) + (s8a[2] + s8a[3]);
        float sB = (s8a[4] + s8a[5]) + (s8a[6] + s8a[7]);
        float ps = sA + sB;
        ps += __shfl_xor(ps, 32);
        l_run += ps;

        // ---- P -> B-frag (col=q, k=key): cvt_pk pairs + lane^32 exchange ----
        unsigned int pw[4][4];
#pragma unroll
        for (int g = 0; g < 2; ++g) {
            unsigned int w[8];
#pragma unroll
            for (int j = 0; j < 8; ++j)
                w[j] = cvtpk(sv[g * 16 + 2 * j], sv[g * 16 + 2 * j + 1]);
#pragma unroll
            for (int u = 0; u < 2; ++u) {
                unsigned int t0 = (unsigned)__shfl_xor((int)w[4 * u + 0], 32);
                unsigned int t1 = (unsigned)__shfl_xor((int)w[4 * u + 1], 32);
                unsigned int t2 = (unsigned)__shfl_xor((int)w[4 * u + 2], 32);
                unsigned int t3 = (unsigned)__shfl_xor((int)w[4 * u + 3], 32);
                pw[2 * g + u][0] = h2 ? t2 : w[4 * u + 0];
                pw[2 * g + u][1] = h2 ? t3 : w[4 * u + 1];
                pw[2 * g + u][2] = h2 ? w[4 * u + 2] : t0;
                pw[2 * g + u][3] = h2 ? w[4 * u + 3] : t1;
            }
        }

        // ---- PV: out^T[d][q] += V^T(32d x 16k) * P^T(16k x 32q) ----
        __builtin_amdgcn_s_setprio(1);
#pragma unroll
        for (int kb = 0; kb < 4; ++kb) {
            u32x4 wv;
            wv[0] = pw[kb][0]; wv[1] = pw[kb][1]; wv[2] = pw[kb][2]; wv[3] = pw[kb][3];
            s8v pf = __builtin_bit_cast(s8v, wv);
#pragma unroll
            for (int dblk = 0; dblk < 4; ++dblk)
                acc[dblk] = __builtin_amdgcn_mfma_f32_32x32x16_bf16(vf[kb][dblk], pf, acc[dblk], 0, 0, 0);
        }
        __builtin_amdgcn_s_setprio(0);

        __syncthreads();
        cur ^= 1;
    }

    // ---- normalize (lane-local) and store out[q][h*128+d] ----
    float inv = 1.f / l_run;
    unsigned short* Op = out + (size_t)(b * S + qq) * 2048 + h * 128 + 4 * h2;
#pragma unroll
    for (int dblk = 0; dblk < 4; ++dblk)
#pragma unroll
        for (int s = 0; s < 4; ++s) {
            u32x2 wv;
            wv[0] = cvtpk(acc[dblk][4 * s + 0] * inv, acc[dblk][4 * s + 1] * inv);
            wv[1] = cvtpk(acc[dblk][4 * s + 2] * inv, acc[dblk][4 * s + 3] * inv);
            *(u32x2*)(Op + 32 * dblk + 8 * s) = wv;
        }
}

// ---------- launch ----------
extern "C" void kernel_launch(void* const* d_in, const int* in_sizes, int n_in,
                              void* d_out, int out_size, void* d_ws, size_t ws_size,
                              hipStream_t stream) {
    const float* x  = (const float*)d_in[0];
    const float* fc = (const float*)d_in[1];
    const float* fs = (const float*)d_in[2];
    const float* wq = (const float*)d_in[4];
    const float* wk = (const float*)d_in[5];
    const float* wv = (const float*)d_in[6];
    const float* wo = (const float*)d_in[7];
    float* out = (float*)d_out;

    char* ws = (char*)d_ws;
    unsigned short* xb    = (unsigned short*)ws;                               // 16 MB (reused as attn out)
    unsigned short* wqkvT = (unsigned short*)(ws + 16777216);                  // 12 MB (reused as V^T)
    unsigned short* woT   = (unsigned short*)(ws + 16777216 + 12582912);       // 8 MB
    unsigned short* qkvb  = (unsigned short*)(ws + 16777216 + 12582912 + 8388608); // 24 MB
    unsigned short* attnb = xb;
    unsigned short* vtb   = wqkvT;      // V^T [2][4][128][2048] = 4 MB, lives after gemm1

    prep_kernel<<<14336, 256, 0, stream>>>(x, wq, wk, wv, wo, xb, wqkvT, woT);
    gemm_bt<unsigned short><<<768, 256, 0, stream>>>(
        xb, wqkvT, qkvb, 4096, 3072, 2048, 3072);
    ropevt_kernel<<<7168, 256, 0, stream>>>(qkvb, fc, fs, vtb);
    attn_kernel<<<512, 256, 0, stream>>>(qkvb, vtb, attnb);
    gemm_bt<float><<<512, 256, 0, stream>>>(
        attnb, woT, out, 4096, 2048, 2048, 2048);
}

// Round 19
// 217.162 us; speedup vs baseline: 1.1788x; 1.0001x over previous
//
#include <hip/hip_runtime.h>
#include <type_traits>

// ---------- types ----------
typedef short s8v   __attribute__((ext_vector_type(8)));   // 8 x bf16 bits
typedef float f32x4 __attribute__((ext_vector_type(4)));
typedef float f32x16 __attribute__((ext_vector_type(16)));
typedef unsigned int u32x2 __attribute__((ext_vector_type(2)));
typedef unsigned int u32x4 __attribute__((ext_vector_type(4)));

__device__ __forceinline__ unsigned short f2bf(float f) {
    unsigned int u = __builtin_bit_cast(unsigned int, f);
    u += 0x7FFF + ((u >> 16) & 1);          // round-to-nearest-even
    return (unsigned short)(u >> 16);
}
__device__ __forceinline__ float bf2f(unsigned short b) {
    unsigned int u = ((unsigned int)b) << 16;
    return __builtin_bit_cast(float, u);
}
__device__ __forceinline__ unsigned int cvtpk(float lo, float hi) {
    unsigned int w;
    asm("v_cvt_pk_bf16_f32 %0, %1, %2" : "=v"(w) : "v"(lo), "v"(hi));
    return w;
}
// bare v_exp_f32: D = 2^S0 (R16/R17 lesson: exp2f = libm multi-inst; __expf = mul+exp).
__device__ __forceinline__ float exp2_hw(float x) {
    return __builtin_amdgcn_exp2f(x);
}

__device__ __forceinline__ void gload16(const void* g, void* l) {
    __builtin_amdgcn_global_load_lds(
        (const __attribute__((address_space(1))) void*)g,
        (__attribute__((address_space(3))) void*)l, 16, 0, 0);
}

// ---------- merged preprocessing: x->bf16 conv + wq/wk/wv transpose + wo transpose ----------
__global__ __launch_bounds__(256)
void prep_kernel(const float* __restrict__ x, const float* __restrict__ wq,
                 const float* __restrict__ wk, const float* __restrict__ wv,
                 const float* __restrict__ wo,
                 unsigned short* __restrict__ xb, unsigned short* __restrict__ wqkvT,
                 unsigned short* __restrict__ woT) {
    __shared__ float tile[32][33];
    const int bid = blockIdx.x;
    if (bid < 4096) {
        int i = bid * 256 + threadIdx.x;
        const f32x4* s4 = (const f32x4*)x;
        f32x4 a = s4[2 * i], b = s4[2 * i + 1];
        s8v o;
        o[0] = (short)f2bf(a[0]); o[1] = (short)f2bf(a[1]);
        o[2] = (short)f2bf(a[2]); o[3] = (short)f2bf(a[3]);
        o[4] = (short)f2bf(b[0]); o[5] = (short)f2bf(b[1]);
        o[6] = (short)f2bf(b[2]); o[7] = (short)f2bf(b[3]);
        *(s8v*)(xb + (size_t)i * 8) = o;
        return;
    }
    const int tx = threadIdx.x & 31, ty = threadIdx.x >> 5;
    const float* src; unsigned short* dst; int sc, N, n0, k0;
    if (bid < 10240) {
        int lb = bid - 4096;
        n0 = (lb % 96) * 32; k0 = (lb / 96) * 32;
        if (n0 < 2048)      { src = wq; sc = n0;        N = 2048; }
        else if (n0 < 2560) { src = wk; sc = n0 - 2048; N = 512;  }
        else                { src = wv; sc = n0 - 2560; N = 512;  }
        dst = wqkvT;
    } else {
        int lb = bid - 10240;
        n0 = (lb % 64) * 32; k0 = (lb / 64) * 32;
        src = wo; sc = n0; N = 2048; dst = woT;
    }
#pragma unroll
    for (int r = 0; r < 4; ++r)
        tile[ty + r * 8][tx] = src[(size_t)(k0 + ty + r * 8) * N + sc + tx];
    __syncthreads();
#pragma unroll
    for (int r = 0; r < 4; ++r)
        dst[(size_t)(n0 + ty + r * 8) * 2048 + k0 + tx] = f2bf(tile[tx][ty + r * 8]);
}

// ---------- RoPE (+q scale*log2e fold) and V->V^T, one launch ----------
__global__ __launch_bounds__(256)
void ropevt_kernel(unsigned short* __restrict__ qkv, const float* __restrict__ fc,
                   const float* __restrict__ fs, unsigned short* __restrict__ vt) {
    __shared__ unsigned short t[32][33];
    const int bid = blockIdx.x;
    if (bid < 5120) {
        int idx = bid * 256 + threadIdx.x;
        int grp = idx & 15;
        int hh = (idx >> 4) % 20;
        int row = idx / (16 * 20);
        int s = row & 2047;
        int col0 = (hh < 16 ? hh * 128 : 2048 + (hh - 16) * 128) + grp * 8;
        unsigned short* p = qkv + (size_t)row * 3072 + col0;
        s8v v = *(const s8v*)p;
        const float* cc = fc + (size_t)s * 64 + grp * 4;
        const float* ss = fs + (size_t)s * 64 + grp * 4;
        const float sc = (hh < 16) ? (0.08838834764831845f * 1.4426950408889634f) : 1.0f;
#pragma unroll
        for (int j = 0; j < 4; ++j) {
            float xe = bf2f((unsigned short)v[2 * j]);
            float xo = bf2f((unsigned short)v[2 * j + 1]);
            float c = cc[j], sn = ss[j];
            v[2 * j]     = (short)f2bf((xe * c - xo * sn) * sc);
            v[2 * j + 1] = (short)f2bf((xe * sn + xo * c) * sc);
        }
        *(s8v*)p = v;
        return;
    }
    int vb = bid - 5120;               // 0..2047
    int s0 = (vb & 127) * 32, c0 = (vb >> 7) * 32;
    int tx = threadIdx.x & 31, ty = threadIdx.x >> 5;
#pragma unroll
    for (int r = 0; r < 4; ++r)
        t[ty + r * 8][tx] = qkv[(size_t)(s0 + ty + r * 8) * 3072 + 2560 + c0 + tx];
    __syncthreads();
    int b = s0 >> 11, s = s0 & 2047;
    size_t dbase = (size_t)(b * 4 + (c0 >> 7)) * 128 + (c0 & 127);
#pragma unroll
    for (int r = 0; r < 4; ++r)
        vt[(dbase + ty + r * 8) * 2048 + s + tx] = t[tx][ty + r * 8];
}

// ---------- GEMM (R14 kernel — measured at the 2-barrier-structure ceiling) ----------
template <typename CT>
__global__ __launch_bounds__(256)
void gemm_bt(const unsigned short* __restrict__ A, const unsigned short* __restrict__ BT,
             CT* __restrict__ C, int M, int N, int K, int ldc) {
    __shared__ unsigned short As[128 * 64];
    __shared__ unsigned short Bs[128 * 64];
    const int tid = threadIdx.x;
    const int wid = tid >> 6, lane = tid & 63;
    const int l31 = lane & 31, h2 = lane >> 5;
    const int nbx = N >> 7;
    const int per = nbx >> 3;
    const int xcd = blockIdx.x & 7;
    const int li  = blockIdx.x >> 3;
    const int bx  = xcd * per + (li % per);
    const int by  = li / per;
    const int brow = by * 128, bcol = bx * 128;
    const int wr = wid >> 1, wc = wid & 1;
    f32x16 acc[2][2] = {};

    for (int kt = 0; kt < K; kt += 64) {
#pragma unroll
        for (int i = 0; i < 4; ++i) {
            int c = i * 256 + tid;
            int row = c >> 3, u = c & 7;
            gload16(A + (size_t)(brow + row) * K + kt + ((u ^ (row & 7)) << 3),
                    As + (size_t)c * 8);
            gload16(BT + (size_t)(bcol + row) * K + kt + ((u ^ (row & 7)) << 3),
                    Bs + (size_t)c * 8);
        }
        __syncthreads();
        s8v a[2][4], b[2][4];
#pragma unroll
        for (int mm = 0; mm < 2; ++mm) {
            int row = wr * 64 + mm * 32 + l31;
#pragma unroll
            for (int ks = 0; ks < 4; ++ks)
                a[mm][ks] = *(const s8v*)(As + (size_t)row * 64 +
                                          (((2 * ks + h2) ^ (row & 7)) << 3));
        }
#pragma unroll
        for (int nn = 0; nn < 2; ++nn) {
            int row = wc * 64 + nn * 32 + l31;
#pragma unroll
            for (int ks = 0; ks < 4; ++ks)
                b[nn][ks] = *(const s8v*)(Bs + (size_t)row * 64 +
                                          (((2 * ks + h2) ^ (row & 7)) << 3));
        }
#pragma unroll
        for (int ks = 0; ks < 4; ++ks)
#pragma unroll
            for (int mm = 0; mm < 2; ++mm)
#pragma unroll
                for (int nn = 0; nn < 2; ++nn)
                    acc[mm][nn] = __builtin_amdgcn_mfma_f32_32x32x16_bf16(
                        a[mm][ks], b[nn][ks], acc[mm][nn], 0, 0, 0);
        __syncthreads();
    }
#pragma unroll
    for (int mm = 0; mm < 2; ++mm)
#pragma unroll
        for (int nn = 0; nn < 2; ++nn)
#pragma unroll
            for (int reg = 0; reg < 16; ++reg) {
                int r = brow + wr * 64 + mm * 32 + (reg & 3) + 8 * (reg >> 2) + 4 * h2;
                int c = bcol + wc * 64 + nn * 32 + l31;
                float v = acc[mm][nn][reg];
                if constexpr (std::is_same<CT, float>::value)
                    C[(size_t)r * ldc + c] = v;
                else
                    C[(size_t)r * ldc + c] = f2bf(v);
            }
}

// ---------- Flash attention (R17-exact body — best measured 92.8us) ----------
// 512 blocks x 256 threads (4 waves = 4 heads of one kvh). blockIdx&7 = (b,kvh).
// qi = 63 - (bid>>3): measured-best. Balance experiments PARKED (R7/R9/R15 all
// regressed). Tree reductions NEUTRAL (R18) -> reverted to keep VGPR at 176.
// Scores pre-scaled by 1/sqrt(128)*log2e (rope fold); softmax = bare v_exp_f32.
// defer-max THR=11.5 (=8*log2e). Mask only on the diagonal tile.
__global__ __launch_bounds__(256)
void attn_kernel(const unsigned short* __restrict__ qkv,
                 const unsigned short* __restrict__ vtg,
                 unsigned short* __restrict__ out) {
    constexpr int S = 2048;
    __shared__ unsigned short Ks[2][64 * 128];   // [key][d-unit8 ^ (key&7)]
    __shared__ unsigned short Vs[2][128 * 64];   // [d][key-unit8 ^ (d&7)]
    const int tid = threadIdx.x, lane = tid & 63, wid = tid >> 6;
    const int l31 = lane & 31, h2 = lane >> 5;
    const int lsw = l31 & 7;
    const int g8 = blockIdx.x & 7;               // (b,kvh) -> XCD pin
    const int b = g8 >> 2, kvh = g8 & 3;
    const int qi = 63 - (blockIdx.x >> 3);       // measured-best ordering
    const int h = kvh * 4 + wid;                 // wave = head
    const int qw = qi * 32;
    const int qq = qw + l31;                     // this lane's q row
    const size_t rs = 3072;

    const unsigned short* Qp = qkv + (size_t)(b * S + qw) * rs + h * 128 + h2 * 8;
    const unsigned short* Kbase = qkv + (size_t)(b * S) * rs + 2048 + kvh * 128;
    const unsigned short* Vtg = vtg + (size_t)((b * 4 + kvh) * 128) * S;

    // Q B-frag: col=q=l31, k = 16*kk + 8*h2 + e
    s8v qf[8];
#pragma unroll
    for (int kk = 0; kk < 8; ++kk)
        qf[kk] = *(const s8v*)(Qp + (size_t)l31 * rs + kk * 16);

    f32x16 acc[4] = {};                          // out^T: acc[dblk], row d, col q
    float m_run = -1e30f, l_run = 0.f;
    const int nt = (qi >> 1) + 1;

    auto stage = [&](int t, int bufi) {
        const int kb64 = t * 64;
#pragma unroll
        for (int i = 0; i < 4; ++i) {            // K tile [64][128]: 1024 chunks of 16B
            int c = i * 256 + tid;
            int key = c >> 4, d8 = c & 15;
            gload16(Kbase + (size_t)(kb64 + key) * rs + ((d8 ^ (key & 7)) << 3),
                    &Ks[bufi][(size_t)c * 8]);
        }
#pragma unroll
        for (int i = 0; i < 4; ++i) {            // V^T tile [128][64]
            int c = i * 256 + tid;
            int d = c >> 3, k8 = c & 7;
            gload16(Vtg + (size_t)d * S + kb64 + ((k8 ^ (d & 7)) << 3),
                    &Vs[bufi][(size_t)c * 8]);
        }
    };

    int cur = 0;
    stage(0, 0);
    __syncthreads();

    for (int t = 0; t < nt; ++t) {
        if (t + 1 < nt) stage(t + 1, cur ^ 1);
        const int kb64 = t * 64;
        const char* Kb = (const char*)&Ks[cur][0];
        const char* Vb = (const char*)&Vs[cur][0];

        // ---- K A-frags from LDS (row=key, k=16kk+8h2+e); conflict-free swizzled ----
        s8v kf0[8], kf1[8];
#pragma unroll
        for (int kk = 0; kk < 8; ++kk)
            kf0[kk] = *(const s8v*)(Kb + l31 * 256 + (((2 * kk + h2) ^ lsw) << 4));
#pragma unroll
        for (int kk = 0; kk < 8; ++kk)
            kf1[kk] = *(const s8v*)(Kb + (32 + l31) * 256 + (((2 * kk + h2) ^ lsw) << 4));
        // ---- V^T A-frags (row=d=32dblk+l31, k=key=16kb+8h2+e) ----
        s8v vf[4][4];
#pragma unroll
        for (int kb = 0; kb < 4; ++kb)
#pragma unroll
            for (int dblk = 0; dblk < 4; ++dblk)
                vf[kb][dblk] = *(const s8v*)(Vb + (32 * dblk + l31) * 128 +
                                             (((2 * kb + h2) ^ lsw) << 4));

        // ---- QK^T (swapped): S^T[key][q], C col = q lane-local ----
        f32x16 sacc0 = {}, sacc1 = {};
        __builtin_amdgcn_s_setprio(1);
#pragma unroll
        for (int kk = 0; kk < 8; ++kk)
            sacc0 = __builtin_amdgcn_mfma_f32_32x32x16_bf16(kf0[kk], qf[kk], sacc0, 0, 0, 0);
#pragma unroll
        for (int kk = 0; kk < 8; ++kk)
            sacc1 = __builtin_amdgcn_mfma_f32_32x32x16_bf16(kf1[kk], qf[kk], sacc1, 0, 0, 0);
        __builtin_amdgcn_s_setprio(0);

        // ---- scores (already log2-domain); mask only on the diagonal tile ----
        float sv[32];
        if (t == nt - 1) {
#pragma unroll
            for (int g = 0; g < 2; ++g)
#pragma unroll
                for (int r = 0; r < 16; ++r) {
                    int key = kb64 + 32 * g + (r & 3) + 8 * (r >> 2) + 4 * h2;
                    float s = (g ? sacc1[r] : sacc0[r]);
                    sv[g * 16 + r] = (key <= qq) ? s : -1e30f;
                }
        } else {
#pragma unroll
            for (int r = 0; r < 16; ++r) sv[r] = sacc0[r];
#pragma unroll
            for (int r = 0; r < 16; ++r) sv[16 + r] = sacc1[r];
        }

        // ---- online softmax (exp2 domain, bare v_exp_f32); defer-max THR=11.5 ----
        float mx = sv[0];
#pragma unroll
        for (int i = 1; i < 32; ++i) mx = fmaxf(mx, sv[i]);
        mx = fmaxf(mx, __shfl_xor(mx, 32));
        if (!__all(mx - m_run <= 11.5f)) {
            float mn = fmaxf(m_run, mx);
            float alpha = exp2_hw(m_run - mn);
            m_run = mn;
            l_run *= alpha;
#pragma unroll
            for (int dblk = 0; dblk < 4; ++dblk)
#pragma unroll
                for (int r = 0; r < 16; ++r) acc[dblk][r] *= alpha;
        }
        float ps = 0.f;
#pragma unroll
        for (int i = 0; i < 32; ++i) {
            float e = exp2_hw(sv[i] - m_run);
            sv[i] = e;
            ps += e;
        }
        ps += __shfl_xor(ps, 32);
        l_run += ps;

        // ---- P -> B-frag (col=q, k=key): cvt_pk pairs + lane^32 exchange ----
        unsigned int pw[4][4];
#pragma unroll
        for (int g = 0; g < 2; ++g) {
            unsigned int w[8];
#pragma unroll
            for (int j = 0; j < 8; ++j)
                w[j] = cvtpk(sv[g * 16 + 2 * j], sv[g * 16 + 2 * j + 1]);
#pragma unroll
            for (int u = 0; u < 2; ++u) {
                unsigned int t0 = (unsigned)__shfl_xor((int)w[4 * u + 0], 32);
                unsigned int t1 = (unsigned)__shfl_xor((int)w[4 * u + 1], 32);
                unsigned int t2 = (unsigned)__shfl_xor((int)w[4 * u + 2], 32);
                unsigned int t3 = (unsigned)__shfl_xor((int)w[4 * u + 3], 32);
                pw[2 * g + u][0] = h2 ? t2 : w[4 * u + 0];
                pw[2 * g + u][1] = h2 ? t3 : w[4 * u + 1];
                pw[2 * g + u][2] = h2 ? w[4 * u + 2] : t0;
                pw[2 * g + u][3] = h2 ? w[4 * u + 3] : t1;
            }
        }

        // ---- PV: out^T[d][q] += V^T(32d x 16k) * P^T(16k x 32q) ----
        __builtin_amdgcn_s_setprio(1);
#pragma unroll
        for (int kb = 0; kb < 4; ++kb) {
            u32x4 wv;
            wv[0] = pw[kb][0]; wv[1] = pw[kb][1]; wv[2] = pw[kb][2]; wv[3] = pw[kb][3];
            s8v pf = __builtin_bit_cast(s8v, wv);
#pragma unroll
            for (int dblk = 0; dblk < 4; ++dblk)
                acc[dblk] = __builtin_amdgcn_mfma_f32_32x32x16_bf16(vf[kb][dblk], pf, acc[dblk], 0, 0, 0);
        }
        __builtin_amdgcn_s_setprio(0);

        __syncthreads();
        cur ^= 1;
    }

    // ---- normalize (lane-local) and store out[q][h*128+d] ----
    float inv = 1.f / l_run;
    unsigned short* Op = out + (size_t)(b * S + qq) * 2048 + h * 128 + 4 * h2;
#pragma unroll
    for (int dblk = 0; dblk < 4; ++dblk)
#pragma unroll
        for (int s = 0; s < 4; ++s) {
            u32x2 wv;
            wv[0] = cvtpk(acc[dblk][4 * s + 0] * inv, acc[dblk][4 * s + 1] * inv);
            wv[1] = cvtpk(acc[dblk][4 * s + 2] * inv, acc[dblk][4 * s + 3] * inv);
            *(u32x2*)(Op + 32 * dblk + 8 * s) = wv;
        }
}

// ---------- launch ----------
extern "C" void kernel_launch(void* const* d_in, const int* in_sizes, int n_in,
                              void* d_out, int out_size, void* d_ws, size_t ws_size,
                              hipStream_t stream) {
    const float* x  = (const float*)d_in[0];
    const float* fc = (const float*)d_in[1];
    const float* fs = (const float*)d_in[2];
    const float* wq = (const float*)d_in[4];
    const float* wv = (const float*)d_in[6];
    const float* wk = (const float*)d_in[5];
    const float* wo = (const float*)d_in[7];
    float* out = (float*)d_out;

    char* ws = (char*)d_ws;
    unsigned short* xb    = (unsigned short*)ws;                               // 16 MB (reused as attn out)
    unsigned short* wqkvT = (unsigned short*)(ws + 16777216);                  // 12 MB (reused as V^T)
    unsigned short* woT   = (unsigned short*)(ws + 16777216 + 12582912);       // 8 MB
    unsigned short* qkvb  = (unsigned short*)(ws + 16777216 + 12582912 + 8388608); // 24 MB
    unsigned short* attnb = xb;
    unsigned short* vtb   = wqkvT;      // V^T [2][4][128][2048] = 4 MB, lives after gemm1

    prep_kernel<<<14336, 256, 0, stream>>>(x, wq, wk, wv, wo, xb, wqkvT, woT);
    gemm_bt<unsigned short><<<768, 256, 0, stream>>>(
        xb, wqkvT, qkvb, 4096, 3072, 2048, 3072);
    ropevt_kernel<<<7168, 256, 0, stream>>>(qkvb, fc, fs, vtb);
    attn_kernel<<<512, 256, 0, stream>>>(qkvb, vtb, attnb);
    gemm_bt<float><<<512, 256, 0, stream>>>(
        attnb, woT, out, 4096, 2048, 2048, 2048);
}